// Round 2
// baseline (421.289 us; speedup 1.0000x reference)
//
#include <hip/hip_runtime.h>

#define B_   8
#define C_   256
#define D_   32
#define N_   4096
#define FMX  64.0f
#define PSTR 528   // Pb part stride in u16: 66 rows * 8. 1056B % 128 = 32 -> q4 groups hit distinct banks

typedef __attribute__((ext_vector_type(8))) short bf8_t;   // 8 bf16 (4 VGPRs)
typedef __attribute__((ext_vector_type(4))) float f4_t;    // MFMA C/D frag

__device__ __forceinline__ unsigned short f2bf(float f) {   // fp32 -> bf16 RNE
    unsigned int u = __builtin_bit_cast(unsigned int, f);
    u += 0x7FFFu + ((u >> 16) & 1u);
    return (unsigned short)(u >> 16);
}
__device__ __forceinline__ float bf2f(unsigned short h) {
    unsigned int u = ((unsigned int)h) << 16;
    return __builtin_bit_cast(float, u);
}
__device__ __forceinline__ uint4 pack8(const unsigned short* h) {
    uint4 u;
    u.x = h[0] | ((unsigned)h[1] << 16); u.y = h[2] | ((unsigned)h[3] << 16);
    u.z = h[4] | ((unsigned)h[5] << 16); u.w = h[6] | ((unsigned)h[7] << 16);
    return u;
}

// ---------------------------------------------------------------------------
// Kernel 0: weight prep -> A-fragment-ordered bf16 (unchanged).
// ---------------------------------------------------------------------------
__global__ __launch_bounds__(256) void wprep_kernel(
    const float* __restrict__ qw, const float* __restrict__ vw,
    unsigned short* __restrict__ wqFh, unsigned short* __restrict__ wqFl,
    unsigned short* __restrict__ wvF)
{
    const int tid = blockIdx.x * 256 + threadIdx.x;   // 36*256 = 9216
    if (tid < 8192) {
        const int k = tid;
        const int rowblk = k >> 9, kk = (k >> 6) & 7, lane = k & 63;
        const int oc = rowblk * 16 + (lane & 15), c0 = kk * 32 + (lane >> 4) * 8;
        const float* src = vw + oc * 256 + c0;
        unsigned short h[8];
        #pragma unroll
        for (int e = 0; e < 8; ++e) h[e] = f2bf(src[e]);
        *(uint4*)(wvF + (size_t)k * 8) = pack8(h);
    } else if (tid < 9216) {
        const int k = tid - 8192;
        const int rowblk = k >> 9, kk = (k >> 6) & 7, lane = k & 63;
        const int oc = rowblk * 16 + (lane & 15), c0 = kk * 32 + (lane >> 4) * 8;
        const float* src = qw + oc * 256 + c0;
        unsigned short h[8], l[8];
        #pragma unroll
        for (int e = 0; e < 8; ++e) {
            h[e] = f2bf(src[e]);
            l[e] = f2bf(src[e] - bf2f(h[e]));
        }
        *(uint4*)(wqFh + (size_t)k * 8) = pack8(h);
        *(uint4*)(wqFl + (size_t)k * 8) = pack8(l);
    }
}

// ---------------------------------------------------------------------------
// Kernel 1: MFMA projections (unchanged from R1; batch->XCD pinning kept —
// attn FETCH_SIZE=29MB confirms the producer->consumer caching works).
// ---------------------------------------------------------------------------
__global__ __launch_bounds__(256, 2) void proj_kernel(
    const float* __restrict__ x, const unsigned short* __restrict__ wqFh,
    const unsigned short* __restrict__ wqFl, const unsigned short* __restrict__ wvF,
    const float* __restrict__ qb, const float* __restrict__ vb,
    unsigned short* __restrict__ qh, unsigned short* __restrict__ ql,
    unsigned short* __restrict__ vT)
{
    __shared__ __align__(16) unsigned short S[18432];

    const int t    = threadIdx.x;
    const int lane = t & 63;
    const int w    = t >> 6;
    const int q4   = lane >> 4;
    const int l15  = lane & 15;
    const int b    = blockIdx.x & 7;          // batch -> XCD pin
    const int tile = blockIdx.x >> 3;
    const int i0   = tile * 64;

    const float* xb = x + (size_t)b * C_ * N_ + i0 + lane;
    #pragma unroll
    for (int cc = 0; cc < 8; ++cc) {
        const int chi = w * 8 + cc;
        float v[8];
        #pragma unroll
        for (int e = 0; e < 8; ++e) v[e] = xb[(size_t)(chi * 8 + e) * N_];
        unsigned short h[8];
        #pragma unroll
        for (int e = 0; e < 8; ++e) h[e] = f2bf(v[e]);
        *(uint4*)&S[(chi * 64 + lane) * 8] = pack8(h);
    }
    __syncthreads();

    f4_t acc[4][4];
    #pragma unroll
    for (int mt = 0; mt < 4; ++mt)
        #pragma unroll
        for (int nt = 0; nt < 4; ++nt) acc[mt][nt] = (f4_t)0.0f;
    f4_t qacc[2];
    qacc[0] = (f4_t)0.0f; qacc[1] = (f4_t)0.0f;

    #pragma unroll
    for (int kk = 0; kk < 8; ++kk) {
        bf8_t Bh[4];
        #pragma unroll
        for (int nt = 0; nt < 4; ++nt)
            Bh[nt] = *(const bf8_t*)&S[((kk * 4 + q4) * 64 + nt * 16 + l15) * 8];
        bf8_t Av[4];
        #pragma unroll
        for (int mt = 0; mt < 4; ++mt)
            Av[mt] = *(const bf8_t*)&wvF[(size_t)(((w * 4 + mt) * 8 + kk) * 64 + lane) * 8];
        bf8_t Aqh[2], Aql[2];
        #pragma unroll
        for (int mq = 0; mq < 2; ++mq) {
            Aqh[mq] = *(const bf8_t*)&wqFh[(size_t)((mq * 8 + kk) * 64 + lane) * 8];
            Aql[mq] = *(const bf8_t*)&wqFl[(size_t)((mq * 8 + kk) * 64 + lane) * 8];
        }

        #pragma unroll
        for (int mt = 0; mt < 4; ++mt)
            #pragma unroll
            for (int nt = 0; nt < 4; ++nt)
                acc[mt][nt] = __builtin_amdgcn_mfma_f32_16x16x32_bf16(
                    Av[mt], Bh[nt], acc[mt][nt], 0, 0, 0);
        #pragma unroll
        for (int mq = 0; mq < 2; ++mq) {
            qacc[mq] = __builtin_amdgcn_mfma_f32_16x16x32_bf16(Aqh[mq], Bh[w], qacc[mq], 0, 0, 0);
            qacc[mq] = __builtin_amdgcn_mfma_f32_16x16x32_bf16(Aql[mq], Bh[w], qacc[mq], 0, 0, 0);
        }
    }

    {
        const int iq = i0 + w * 16 + l15;
        #pragma unroll
        for (int mq = 0; mq < 2; ++mq) {
            float4 qb4 = *(const float4*)(qb + mq * 16 + q4 * 4);
            float qv[4] = {qacc[mq][0] + qb4.x, qacc[mq][1] + qb4.y,
                           qacc[mq][2] + qb4.z, qacc[mq][3] + qb4.w};
            unsigned short hr[4], lr[4];
            #pragma unroll
            for (int r = 0; r < 4; ++r) {
                hr[r] = f2bf(qv[r]);
                lr[r] = f2bf(qv[r] - bf2f(hr[r]));
            }
            uint2 uh, ul;
            uh.x = hr[0] | ((unsigned)hr[1] << 16); uh.y = hr[2] | ((unsigned)hr[3] << 16);
            ul.x = lr[0] | ((unsigned)lr[1] << 16); ul.y = lr[2] | ((unsigned)lr[3] << 16);
            size_t qoff = ((size_t)b * N_ + iq) * D_ + mq * 16 + q4 * 4;
            *(uint2*)(qh + qoff) = uh;
            *(uint2*)(ql + qoff) = ul;
        }
    }

    __syncthreads();
    #pragma unroll
    for (int mt = 0; mt < 4; ++mt) {
        float4 vb4 = *(const float4*)(vb + w * 64 + mt * 16 + q4 * 4);
        float bias[4] = {vb4.x, vb4.y, vb4.z, vb4.w};
        #pragma unroll
        for (int nt = 0; nt < 4; ++nt)
            #pragma unroll
            for (int r = 0; r < 4; ++r)
                S[(w * 64 + mt * 16 + q4 * 4 + r) * 72 + nt * 16 + l15] =
                    f2bf(acc[mt][nt][r] + bias[r]);
    }
    __syncthreads();
    #pragma unroll
    for (int k2 = 0; k2 < 8; ++k2) {
        int id = k2 * 256 + t;
        int oc = id >> 3, seg = id & 7;
        uint4 dat = *(const uint4*)&S[oc * 72 + seg * 8];
        *(uint4*)(vT + ((size_t)b * C_ + oc) * N_ + i0 + seg * 8) = dat;   // c-major
    }
}

// ---------------------------------------------------------------------------
// Kernel 2: MFMA flash attention.
// R2 CHANGES (counter-driven):
//  (a) Pb part stride 64 -> 66 rows (PSTR=528 u16, 1056B % 128 = 32):
//      Af ds_read_b128 was 4-way bank-conflicted (1024B % 128 == 0 aliased all
//      q4 groups); P ds_write_b16 was ~8-way (dword stride 256 % 32 == 0).
//      Now reads conflict-free, writes ~4-way (2-way free per m136).
//      SQ_LDS_BANK_CONFLICT was 8.9M cyc (~14.5us/CU = 11% of kernel).
//  (b) Double-buffered Vs + register prefetch of the NEXT V tile issued
//      BEFORE the QK/exp phase (T14 async-stage split): L2 load latency hides
//      under QK MFMA + exp instead of sitting between the two barriers.
//      LDS 74.5KB -> still 2 blocks/CU.
// ---------------------------------------------------------------------------
__global__ __launch_bounds__(256, 2) void attn_kernel(
    const unsigned short* __restrict__ qh, const unsigned short* __restrict__ ql,
    const unsigned short* __restrict__ vT, const float* __restrict__ x,
    const float* __restrict__ gamma_p, float* __restrict__ out)
{
    __shared__ __align__(16) unsigned short Vs[2][8 * 257 * 8];
    __shared__ __align__(16) unsigned short Pb[8 * PSTR];
    __shared__ __align__(16) float rowl[64];

    float* T = (float*)Vs;

    const int t    = threadIdx.x;
    const int lane = t & 63;
    const int w    = t >> 6;
    const int q4   = lane >> 4;
    const int l15  = lane & 15;
    const int b    = blockIdx.x & 7;              // batch -> XCD pin
    const int i0   = (blockIdx.x >> 3) * 64;

    const unsigned short* qhb = qh + (size_t)b * N_ * D_;
    const unsigned short* qlb = ql + (size_t)b * N_ * D_;
    const unsigned short* vTb = vT + (size_t)b * C_ * N_;

    // staging geometry: thread t, pass r covers (channel c, j-part)
    const int sc[8] = {  (0*256+t)>>3, (1*256+t)>>3, (2*256+t)>>3, (3*256+t)>>3,
                         (4*256+t)>>3, (5*256+t)>>3, (6*256+t)>>3, (7*256+t)>>3 };
    const int spart = t & 7;

    bf8_t Ah[4], Al[4];
    #pragma unroll
    for (int mt = 0; mt < 4; ++mt) {
        size_t off = (size_t)(i0 + mt * 16 + l15) * D_ + q4 * 8;
        Ah[mt] = *(const bf8_t*)(qhb + off);
        Al[mt] = *(const bf8_t*)(qlb + off);
    }

    f4_t acc[4][4];
    #pragma unroll
    for (int mt = 0; mt < 4; ++mt)
        #pragma unroll
        for (int nt = 0; nt < 4; ++nt) acc[mt][nt] = (f4_t)0.0f;

    f4_t lacc[4];
    #pragma unroll
    for (int mt = 0; mt < 4; ++mt) lacc[mt] = (f4_t)0.0f;
    bf8_t onesb;
    #pragma unroll
    for (int e = 0; e < 8; ++e) onesb[e] = (short)0x3F80;

    // ---- prologue: stage V tile 0 into Vs[0] (visible after first in-loop
    //      pair of barriers, before any PV read of Vs[0]) ----
    uint4 vreg[8];
    #pragma unroll
    for (int r = 0; r < 8; ++r)
        vreg[r] = *(const uint4*)(vTb + (size_t)sc[r] * N_ + spart * 8);
    #pragma unroll
    for (int r = 0; r < 8; ++r)
        *(uint4*)(&Vs[0][(spart * 257 + sc[r]) * 8]) = vreg[r];

    for (int jt = 0; jt < N_ / 64; ++jt) {
        const int j0  = jt * 64;
        const int cur = jt & 1;

        // K fragment loads for this tile (issued first -> ready at vmcnt(8))
        size_t koff = (size_t)(j0 + w * 16 + l15) * D_ + q4 * 8;
        bf8_t Bh = *(const bf8_t*)(qhb + koff);
        bf8_t Bl = *(const bf8_t*)(qlb + koff);

        // prefetch NEXT V tile into registers; latency hides under QK + exp
        if (jt + 1 < N_ / 64) {
            #pragma unroll
            for (int r = 0; r < 8; ++r)
                vreg[r] = *(const uint4*)(vTb + (size_t)sc[r] * N_ + (j0 + 64) + spart * 8);
        }

        f4_t s[4];
        #pragma unroll
        for (int mt = 0; mt < 4; ++mt) {
            f4_t a = (f4_t)0.0f;
            a = __builtin_amdgcn_mfma_f32_16x16x32_bf16(Ah[mt], Bh, a, 0, 0, 0);
            a = __builtin_amdgcn_mfma_f32_16x16x32_bf16(Ah[mt], Bl, a, 0, 0, 0);
            a = __builtin_amdgcn_mfma_f32_16x16x32_bf16(Al[mt], Bh, a, 0, 0, 0);
            s[mt] = a;
        }

        // exp + bf16 convert BEFORE the barrier (keep critical section short)
        unsigned short pu[4][4];
        #pragma unroll
        for (int mt = 0; mt < 4; ++mt)
            #pragma unroll
            for (int r = 0; r < 4; ++r)
                pu[mt][r] = f2bf(__expf(s[mt][r] - FMX));

        __syncthreads();   // PV(jt-1) done reading Pb and Vs[(jt+1)&1]

        const int jl = w * 16 + l15;
        const int pprt = jl >> 3, jlo = jl & 7;
        #pragma unroll
        for (int mt = 0; mt < 4; ++mt)
            #pragma unroll
            for (int r = 0; r < 4; ++r)
                Pb[pprt * PSTR + (mt * 16 + q4 * 4 + r) * 8 + jlo] = pu[mt][r];

        if (jt + 1 < N_ / 64) {
            #pragma unroll
            for (int r = 0; r < 8; ++r)
                *(uint4*)(&Vs[cur ^ 1][(spart * 257 + sc[r]) * 8]) = vreg[r];
        }

        __syncthreads();   // Pb(jt) visible; Vs[cur] was synced last iteration

        #pragma unroll
        for (int kk = 0; kk < 2; ++kk) {
            bf8_t Af[4], Bf[4];
            #pragma unroll
            for (int mt = 0; mt < 4; ++mt)
                Af[mt] = *(const bf8_t*)(&Pb[(kk * 4 + q4) * PSTR + (mt * 16 + l15) * 8]);
            #pragma unroll
            for (int nt = 0; nt < 4; ++nt)
                Bf[nt] = *(const bf8_t*)(&Vs[cur][((kk * 4 + q4) * 257 + w * 64 + nt * 16 + l15) * 8]);
            #pragma unroll
            for (int mt = 0; mt < 4; ++mt)
                #pragma unroll
                for (int nt = 0; nt < 4; ++nt)
                    acc[mt][nt] = __builtin_amdgcn_mfma_f32_16x16x32_bf16(
                        Af[mt], Bf[nt], acc[mt][nt], 0, 0, 0);
            if (w == 3) {
                #pragma unroll
                for (int mt = 0; mt < 4; ++mt)
                    lacc[mt] = __builtin_amdgcn_mfma_f32_16x16x32_bf16(
                        Af[mt], onesb, lacc[mt], 0, 0, 0);
            }
        }
    }

    __syncthreads();
    if (w == 3 && l15 == 0) {
        #pragma unroll
        for (int mt = 0; mt < 4; ++mt)
            #pragma unroll
            for (int r = 0; r < 4; ++r)
                rowl[mt * 16 + q4 * 4 + r] = lacc[mt][r];
    }
    __syncthreads();

    const float g = gamma_p[0];
    for (int mt = 0; mt < 4; ++mt) {
        float4 rl = *(float4*)(&rowl[mt * 16 + q4 * 4]);
        float inv[4] = { g / rl.x, g / rl.y, g / rl.z, g / rl.w };
        #pragma unroll
        for (int nt = 0; nt < 4; ++nt)
            #pragma unroll
            for (int r = 0; r < 4; ++r)
                T[(w * 64 + nt * 16 + l15) * 17 + q4 * 4 + r] = acc[mt][nt][r] * inv[r];
        __syncthreads();
        #pragma unroll
        for (int pass = 0; pass < 4; ++pass) {
            int c  = pass * 64 + (t >> 2);
            int ii = (t & 3) * 4;
            float4 o;
            o.x = T[c * 17 + ii];     o.y = T[c * 17 + ii + 1];
            o.z = T[c * 17 + ii + 2]; o.w = T[c * 17 + ii + 3];
            size_t goff = ((size_t)b * C_ + c) * N_ + i0 + mt * 16 + ii;
            float4 xv = *(const float4*)(x + goff);
            o.x += xv.x; o.y += xv.y; o.z += xv.z; o.w += xv.w;
            *(float4*)(out + goff) = o;
        }
        __syncthreads();
    }
}

extern "C" void kernel_launch(void* const* d_in, const int* in_sizes, int n_in,
                              void* d_out, int out_size, void* d_ws, size_t ws_size,
                              hipStream_t stream)
{
    const float* x     = (const float*)d_in[0];
    const float* q_w   = (const float*)d_in[1];
    const float* q_b   = (const float*)d_in[2];
    const float* v_w   = (const float*)d_in[3];
    const float* v_b   = (const float*)d_in[4];
    const float* gamma = (const float*)d_in[5];
    float* out = (float*)d_out;

    unsigned short* ws16 = (unsigned short*)d_ws;
    unsigned short* qhp  = ws16;                   // 1M u16
    unsigned short* qlp  = ws16 + 1048576;         // 1M u16
    unsigned short* vTp  = ws16 + 2097152;         // 8M u16 (c-major V)
    unsigned short* wvF  = ws16 + 10485760;        // 64K u16
    unsigned short* wqFh = wvF + 65536;            // 8K u16
    unsigned short* wqFl = wqFh + 8192;            // 8K u16

    wprep_kernel<<<36, 256, 0, stream>>>(q_w, v_w, wqFh, wqFl, wvF);
    proj_kernel<<<B_ * (N_ / 64), 256, 0, stream>>>(x, wqFh, wqFl, wvF, q_b, v_b,
                                                    qhp, qlp, vTp);
    attn_kernel<<<B_ * (N_ / 64), 256, 0, stream>>>(qhp, qlp, vTp, x, gamma, out);
}

// Round 3
// 340.568 us; speedup vs baseline: 1.2370x; 1.2370x over previous
//
#include <hip/hip_runtime.h>

#define B_   8
#define C_   256
#define D_   32
#define N_   4096
#define FMX  64.0f
#define QBLK 32    // q-rows per block (was 64): 1024 blocks -> 4 blocks/CU

typedef __attribute__((ext_vector_type(8))) short bf8_t;   // 8 bf16 (4 VGPRs)
typedef __attribute__((ext_vector_type(4))) float f4_t;    // MFMA C/D frag

__device__ __forceinline__ unsigned short f2bf(float f) {   // fp32 -> bf16 RNE
    unsigned int u = __builtin_bit_cast(unsigned int, f);
    u += 0x7FFFu + ((u >> 16) & 1u);
    return (unsigned short)(u >> 16);
}
__device__ __forceinline__ float bf2f(unsigned short h) {
    unsigned int u = ((unsigned int)h) << 16;
    return __builtin_bit_cast(float, u);
}
__device__ __forceinline__ uint4 pack8(const unsigned short* h) {
    uint4 u;
    u.x = h[0] | ((unsigned)h[1] << 16); u.y = h[2] | ((unsigned)h[3] << 16);
    u.z = h[4] | ((unsigned)h[5] << 16); u.w = h[6] | ((unsigned)h[7] << 16);
    return u;
}

// ---------------------------------------------------------------------------
// Kernel 0: weight prep -> A-fragment-ordered bf16 (unchanged).
// ---------------------------------------------------------------------------
__global__ __launch_bounds__(256) void wprep_kernel(
    const float* __restrict__ qw, const float* __restrict__ vw,
    unsigned short* __restrict__ wqFh, unsigned short* __restrict__ wqFl,
    unsigned short* __restrict__ wvF)
{
    const int tid = blockIdx.x * 256 + threadIdx.x;   // 36*256 = 9216
    if (tid < 8192) {
        const int k = tid;
        const int rowblk = k >> 9, kk = (k >> 6) & 7, lane = k & 63;
        const int oc = rowblk * 16 + (lane & 15), c0 = kk * 32 + (lane >> 4) * 8;
        const float* src = vw + oc * 256 + c0;
        unsigned short h[8];
        #pragma unroll
        for (int e = 0; e < 8; ++e) h[e] = f2bf(src[e]);
        *(uint4*)(wvF + (size_t)k * 8) = pack8(h);
    } else if (tid < 9216) {
        const int k = tid - 8192;
        const int rowblk = k >> 9, kk = (k >> 6) & 7, lane = k & 63;
        const int oc = rowblk * 16 + (lane & 15), c0 = kk * 32 + (lane >> 4) * 8;
        const float* src = qw + oc * 256 + c0;
        unsigned short h[8], l[8];
        #pragma unroll
        for (int e = 0; e < 8; ++e) {
            h[e] = f2bf(src[e]);
            l[e] = f2bf(src[e] - bf2f(h[e]));
        }
        *(uint4*)(wqFh + (size_t)k * 8) = pack8(h);
        *(uint4*)(wqFl + (size_t)k * 8) = pack8(l);
    }
}

// ---------------------------------------------------------------------------
// Kernel 1: MFMA projections (unchanged; XCD pin kept).
// ---------------------------------------------------------------------------
__global__ __launch_bounds__(256, 2) void proj_kernel(
    const float* __restrict__ x, const unsigned short* __restrict__ wqFh,
    const unsigned short* __restrict__ wqFl, const unsigned short* __restrict__ wvF,
    const float* __restrict__ qb, const float* __restrict__ vb,
    unsigned short* __restrict__ qh, unsigned short* __restrict__ ql,
    unsigned short* __restrict__ vT)
{
    __shared__ __align__(16) unsigned short S[18432];

    const int t    = threadIdx.x;
    const int lane = t & 63;
    const int w    = t >> 6;
    const int q4   = lane >> 4;
    const int l15  = lane & 15;
    const int b    = blockIdx.x & 7;          // batch -> XCD pin
    const int tile = blockIdx.x >> 3;
    const int i0   = tile * 64;

    const float* xb = x + (size_t)b * C_ * N_ + i0 + lane;
    #pragma unroll
    for (int cc = 0; cc < 8; ++cc) {
        const int chi = w * 8 + cc;
        float v[8];
        #pragma unroll
        for (int e = 0; e < 8; ++e) v[e] = xb[(size_t)(chi * 8 + e) * N_];
        unsigned short h[8];
        #pragma unroll
        for (int e = 0; e < 8; ++e) h[e] = f2bf(v[e]);
        *(uint4*)&S[(chi * 64 + lane) * 8] = pack8(h);
    }
    __syncthreads();

    f4_t acc[4][4];
    #pragma unroll
    for (int mt = 0; mt < 4; ++mt)
        #pragma unroll
        for (int nt = 0; nt < 4; ++nt) acc[mt][nt] = (f4_t)0.0f;
    f4_t qacc[2];
    qacc[0] = (f4_t)0.0f; qacc[1] = (f4_t)0.0f;

    #pragma unroll
    for (int kk = 0; kk < 8; ++kk) {
        bf8_t Bh[4];
        #pragma unroll
        for (int nt = 0; nt < 4; ++nt)
            Bh[nt] = *(const bf8_t*)&S[((kk * 4 + q4) * 64 + nt * 16 + l15) * 8];
        bf8_t Av[4];
        #pragma unroll
        for (int mt = 0; mt < 4; ++mt)
            Av[mt] = *(const bf8_t*)&wvF[(size_t)(((w * 4 + mt) * 8 + kk) * 64 + lane) * 8];
        bf8_t Aqh[2], Aql[2];
        #pragma unroll
        for (int mq = 0; mq < 2; ++mq) {
            Aqh[mq] = *(const bf8_t*)&wqFh[(size_t)((mq * 8 + kk) * 64 + lane) * 8];
            Aql[mq] = *(const bf8_t*)&wqFl[(size_t)((mq * 8 + kk) * 64 + lane) * 8];
        }

        #pragma unroll
        for (int mt = 0; mt < 4; ++mt)
            #pragma unroll
            for (int nt = 0; nt < 4; ++nt)
                acc[mt][nt] = __builtin_amdgcn_mfma_f32_16x16x32_bf16(
                    Av[mt], Bh[nt], acc[mt][nt], 0, 0, 0);
        #pragma unroll
        for (int mq = 0; mq < 2; ++mq) {
            qacc[mq] = __builtin_amdgcn_mfma_f32_16x16x32_bf16(Aqh[mq], Bh[w], qacc[mq], 0, 0, 0);
            qacc[mq] = __builtin_amdgcn_mfma_f32_16x16x32_bf16(Aql[mq], Bh[w], qacc[mq], 0, 0, 0);
        }
    }

    {
        const int iq = i0 + w * 16 + l15;
        #pragma unroll
        for (int mq = 0; mq < 2; ++mq) {
            float4 qb4 = *(const float4*)(qb + mq * 16 + q4 * 4);
            float qv[4] = {qacc[mq][0] + qb4.x, qacc[mq][1] + qb4.y,
                           qacc[mq][2] + qb4.z, qacc[mq][3] + qb4.w};
            unsigned short hr[4], lr[4];
            #pragma unroll
            for (int r = 0; r < 4; ++r) {
                hr[r] = f2bf(qv[r]);
                lr[r] = f2bf(qv[r] - bf2f(hr[r]));
            }
            uint2 uh, ul;
            uh.x = hr[0] | ((unsigned)hr[1] << 16); uh.y = hr[2] | ((unsigned)hr[3] << 16);
            ul.x = lr[0] | ((unsigned)lr[1] << 16); ul.y = lr[2] | ((unsigned)lr[3] << 16);
            size_t qoff = ((size_t)b * N_ + iq) * D_ + mq * 16 + q4 * 4;
            *(uint2*)(qh + qoff) = uh;
            *(uint2*)(ql + qoff) = ul;
        }
    }

    __syncthreads();
    #pragma unroll
    for (int mt = 0; mt < 4; ++mt) {
        float4 vb4 = *(const float4*)(vb + w * 64 + mt * 16 + q4 * 4);
        float bias[4] = {vb4.x, vb4.y, vb4.z, vb4.w};
        #pragma unroll
        for (int nt = 0; nt < 4; ++nt)
            #pragma unroll
            for (int r = 0; r < 4; ++r)
                S[(w * 64 + mt * 16 + q4 * 4 + r) * 72 + nt * 16 + l15] =
                    f2bf(acc[mt][nt][r] + bias[r]);
    }
    __syncthreads();
    #pragma unroll
    for (int k2 = 0; k2 < 8; ++k2) {
        int id = k2 * 256 + t;
        int oc = id >> 3, seg = id & 7;
        uint4 dat = *(const uint4*)&S[oc * 72 + seg * 8];
        *(uint4*)(vT + ((size_t)b * C_ + oc) * N_ + i0 + seg * 8) = dat;   // c-major
    }
}

// ---------------------------------------------------------------------------
// Kernel 2: MFMA flash attention.
// R3: REVERT to the R1 (135us) structure verbatim — R2's reg-prefetch double
// buffer spilled to scratch (WRITE_SIZE 34MB->340MB, MfmaUtil 31->12.7%).
// ONE change: QBLK 64 -> 32. Grid 512 -> 1024 blocks = 4 blocks/CU (was 2);
// LDS 41KB -> 37KB so 4 fit; acc shrinks 64->32 VGPRs so (256,4) compiles
// without spill. Same total MFMA work; cross-block overlap now hides the
// 2-barrier-per-jt phase stalls (R1: 40% no-issue cycles, occupancy 19%).
// ---------------------------------------------------------------------------
__global__ __launch_bounds__(256, 4) void attn_kernel(
    const unsigned short* __restrict__ qh, const unsigned short* __restrict__ ql,
    const unsigned short* __restrict__ vT, const float* __restrict__ x,
    const float* __restrict__ gamma_p, float* __restrict__ out)
{
    __shared__ __align__(16) unsigned short Vs[8 * 257 * 8];   // 32896 B
    __shared__ __align__(16) unsigned short Pb[8 * 32 * 8];    //  4096 B
    __shared__ __align__(16) float rowl[QBLK];

    float* T = (float*)Vs;

    const int t    = threadIdx.x;
    const int lane = t & 63;
    const int w    = t >> 6;
    const int q4   = lane >> 4;
    const int l15  = lane & 15;
    const int b    = blockIdx.x & 7;              // batch -> XCD pin
    const int i0   = (blockIdx.x >> 3) * QBLK;

    const unsigned short* qhb = qh + (size_t)b * N_ * D_;
    const unsigned short* qlb = ql + (size_t)b * N_ * D_;
    const unsigned short* vTb = vT + (size_t)b * C_ * N_;

    bf8_t Ah[2], Al[2];
    #pragma unroll
    for (int mt = 0; mt < 2; ++mt) {
        size_t off = (size_t)(i0 + mt * 16 + l15) * D_ + q4 * 8;
        Ah[mt] = *(const bf8_t*)(qhb + off);
        Al[mt] = *(const bf8_t*)(qlb + off);
    }

    f4_t acc[2][4];
    #pragma unroll
    for (int mt = 0; mt < 2; ++mt)
        #pragma unroll
        for (int nt = 0; nt < 4; ++nt) acc[mt][nt] = (f4_t)0.0f;

    f4_t lacc[2];
    lacc[0] = (f4_t)0.0f; lacc[1] = (f4_t)0.0f;
    bf8_t onesb;
    #pragma unroll
    for (int e = 0; e < 8; ++e) onesb[e] = (short)0x3F80;

    for (int jt = 0; jt < N_ / 64; ++jt) {
        const int j0 = jt * 64;

        size_t koff = (size_t)(j0 + w * 16 + l15) * D_ + q4 * 8;
        bf8_t Bh = *(const bf8_t*)(qhb + koff);
        bf8_t Bl = *(const bf8_t*)(qlb + koff);

        __syncthreads();

        #pragma unroll
        for (int r = 0; r < 8; ++r) {
            int idx = r * 256 + t;
            int c = idx >> 3, part = idx & 7;
            uint4 d = *(const uint4*)(vTb + (size_t)c * N_ + j0 + part * 8);
            *(uint4*)(&Vs[(part * 257 + c) * 8]) = d;
        }

        f4_t s[2];
        #pragma unroll
        for (int mt = 0; mt < 2; ++mt) {
            f4_t a = (f4_t)0.0f;
            a = __builtin_amdgcn_mfma_f32_16x16x32_bf16(Ah[mt], Bh, a, 0, 0, 0);
            a = __builtin_amdgcn_mfma_f32_16x16x32_bf16(Ah[mt], Bl, a, 0, 0, 0);
            a = __builtin_amdgcn_mfma_f32_16x16x32_bf16(Al[mt], Bh, a, 0, 0, 0);
            s[mt] = a;
        }

        const int jl = w * 16 + l15;
        const int pprt = jl >> 3, jlo = jl & 7;
        #pragma unroll
        for (int mt = 0; mt < 2; ++mt)
            #pragma unroll
            for (int r = 0; r < 4; ++r) {
                float p = __expf(s[mt][r] - FMX);
                Pb[(pprt * 32 + mt * 16 + q4 * 4 + r) * 8 + jlo] = f2bf(p);
            }

        __syncthreads();

        #pragma unroll
        for (int kk = 0; kk < 2; ++kk) {
            bf8_t Af[2], Bf[4];
            #pragma unroll
            for (int mt = 0; mt < 2; ++mt)
                Af[mt] = *(const bf8_t*)(&Pb[((kk * 4 + q4) * 32 + mt * 16 + l15) * 8]);
            #pragma unroll
            for (int nt = 0; nt < 4; ++nt)
                Bf[nt] = *(const bf8_t*)(&Vs[((kk * 4 + q4) * 257 + w * 64 + nt * 16 + l15) * 8]);
            #pragma unroll
            for (int mt = 0; mt < 2; ++mt)
                #pragma unroll
                for (int nt = 0; nt < 4; ++nt)
                    acc[mt][nt] = __builtin_amdgcn_mfma_f32_16x16x32_bf16(
                        Af[mt], Bf[nt], acc[mt][nt], 0, 0, 0);
            if (w == 3) {
                #pragma unroll
                for (int mt = 0; mt < 2; ++mt)
                    lacc[mt] = __builtin_amdgcn_mfma_f32_16x16x32_bf16(
                        Af[mt], onesb, lacc[mt], 0, 0, 0);
            }
        }
    }

    __syncthreads();
    if (w == 3 && l15 == 0) {
        #pragma unroll
        for (int mt = 0; mt < 2; ++mt)
            #pragma unroll
            for (int r = 0; r < 4; ++r)
                rowl[mt * 16 + q4 * 4 + r] = lacc[mt][r];
    }
    __syncthreads();

    const float g = gamma_p[0];
    for (int mt = 0; mt < 2; ++mt) {
        float4 rl = *(float4*)(&rowl[mt * 16 + q4 * 4]);
        float inv[4] = { g / rl.x, g / rl.y, g / rl.z, g / rl.w };
        #pragma unroll
        for (int nt = 0; nt < 4; ++nt)
            #pragma unroll
            for (int r = 0; r < 4; ++r)
                T[(w * 64 + nt * 16 + l15) * 17 + q4 * 4 + r] = acc[mt][nt][r] * inv[r];
        __syncthreads();
        #pragma unroll
        for (int pass = 0; pass < 4; ++pass) {
            int c  = pass * 64 + (t >> 2);
            int ii = (t & 3) * 4;
            float4 o;
            o.x = T[c * 17 + ii];     o.y = T[c * 17 + ii + 1];
            o.z = T[c * 17 + ii + 2]; o.w = T[c * 17 + ii + 3];
            size_t goff = ((size_t)b * C_ + c) * N_ + i0 + mt * 16 + ii;
            float4 xv = *(const float4*)(x + goff);
            o.x += xv.x; o.y += xv.y; o.z += xv.z; o.w += xv.w;
            *(float4*)(out + goff) = o;
        }
        __syncthreads();
    }
}

extern "C" void kernel_launch(void* const* d_in, const int* in_sizes, int n_in,
                              void* d_out, int out_size, void* d_ws, size_t ws_size,
                              hipStream_t stream)
{
    const float* x     = (const float*)d_in[0];
    const float* q_w   = (const float*)d_in[1];
    const float* q_b   = (const float*)d_in[2];
    const float* v_w   = (const float*)d_in[3];
    const float* v_b   = (const float*)d_in[4];
    const float* gamma = (const float*)d_in[5];
    float* out = (float*)d_out;

    unsigned short* ws16 = (unsigned short*)d_ws;
    unsigned short* qhp  = ws16;                   // 1M u16
    unsigned short* qlp  = ws16 + 1048576;         // 1M u16
    unsigned short* vTp  = ws16 + 2097152;         // 8M u16 (c-major V)
    unsigned short* wvF  = ws16 + 10485760;        // 64K u16
    unsigned short* wqFh = wvF + 65536;            // 8K u16
    unsigned short* wqFl = wqFh + 8192;            // 8K u16

    wprep_kernel<<<36, 256, 0, stream>>>(q_w, v_w, wqFh, wqFl, wvF);
    proj_kernel<<<B_ * (N_ / 64), 256, 0, stream>>>(x, wqFh, wqFl, wvF, q_b, v_b,
                                                    qhp, qlp, vTp);
    attn_kernel<<<B_ * (N_ / QBLK), 256, 0, stream>>>(qhp, qlp, vTp, x, gamma, out);
}

// Round 4
// 282.066 us; speedup vs baseline: 1.4936x; 1.2074x over previous
//
#include <hip/hip_runtime.h>

#define B_   8
#define C_   256
#define D_   32
#define N_   4096
#define FMX  64.0f
// Pb XOR swizzle on the 16B-unit index: spreads q4/mt into low bank bits on
// the scalar u16 write side; read side stays bank-uniform. Involution.
#define PSWZ(u) ((u) ^ (((u) >> 3) & 7))

typedef __attribute__((ext_vector_type(8))) short bf8_t;   // 8 bf16 (4 VGPRs)
typedef __attribute__((ext_vector_type(4))) float f4_t;    // MFMA C/D frag

__device__ __forceinline__ unsigned short f2bf(float f) {   // fp32 -> bf16 RNE
    unsigned int u = __builtin_bit_cast(unsigned int, f);
    u += 0x7FFFu + ((u >> 16) & 1u);
    return (unsigned short)(u >> 16);
}
__device__ __forceinline__ float bf2f(unsigned short h) {
    unsigned int u = ((unsigned int)h) << 16;
    return __builtin_bit_cast(float, u);
}
__device__ __forceinline__ uint4 pack8(const unsigned short* h) {
    uint4 u;
    u.x = h[0] | ((unsigned)h[1] << 16); u.y = h[2] | ((unsigned)h[3] << 16);
    u.z = h[4] | ((unsigned)h[5] << 16); u.w = h[6] | ((unsigned)h[7] << 16);
    return u;
}

// ---------------------------------------------------------------------------
// Kernel 0: weight prep -> A-fragment-ordered bf16 (unchanged).
// ---------------------------------------------------------------------------
__global__ __launch_bounds__(256) void wprep_kernel(
    const float* __restrict__ qw, const float* __restrict__ vw,
    unsigned short* __restrict__ wqFh, unsigned short* __restrict__ wqFl,
    unsigned short* __restrict__ wvF)
{
    const int tid = blockIdx.x * 256 + threadIdx.x;   // 36*256 = 9216
    if (tid < 8192) {
        const int k = tid;
        const int rowblk = k >> 9, kk = (k >> 6) & 7, lane = k & 63;
        const int oc = rowblk * 16 + (lane & 15), c0 = kk * 32 + (lane >> 4) * 8;
        const float* src = vw + oc * 256 + c0;
        unsigned short h[8];
        #pragma unroll
        for (int e = 0; e < 8; ++e) h[e] = f2bf(src[e]);
        *(uint4*)(wvF + (size_t)k * 8) = pack8(h);
    } else if (tid < 9216) {
        const int k = tid - 8192;
        const int rowblk = k >> 9, kk = (k >> 6) & 7, lane = k & 63;
        const int oc = rowblk * 16 + (lane & 15), c0 = kk * 32 + (lane >> 4) * 8;
        const float* src = qw + oc * 256 + c0;
        unsigned short h[8], l[8];
        #pragma unroll
        for (int e = 0; e < 8; ++e) {
            h[e] = f2bf(src[e]);
            l[e] = f2bf(src[e] - bf2f(h[e]));
        }
        *(uint4*)(wqFh + (size_t)k * 8) = pack8(h);
        *(uint4*)(wqFl + (size_t)k * 8) = pack8(l);
    }
}

// ---------------------------------------------------------------------------
// Kernel 1: MFMA projections.
// R4 CHANGE: V output now written in MFMA-B-FRAGMENT order vF[b][tile][p][c][e]
// = V[c][tile*64 + p*8 + e] (the exact layout attn's old LDS transpose
// produced), so attn can load B-fragments directly from L2 with no LDS
// staging. Copy mapping (oc = t, seg = k2): global writes are 1KB-contiguous
// per wave; LDS reads at stride 72 are bank-uniform for b128.
// ---------------------------------------------------------------------------
__global__ __launch_bounds__(256, 2) void proj_kernel(
    const float* __restrict__ x, const unsigned short* __restrict__ wqFh,
    const unsigned short* __restrict__ wqFl, const unsigned short* __restrict__ wvF,
    const float* __restrict__ qb, const float* __restrict__ vb,
    unsigned short* __restrict__ qh, unsigned short* __restrict__ ql,
    unsigned short* __restrict__ vF)
{
    __shared__ __align__(16) unsigned short S[18432];

    const int t    = threadIdx.x;
    const int lane = t & 63;
    const int w    = t >> 6;
    const int q4   = lane >> 4;
    const int l15  = lane & 15;
    const int b    = blockIdx.x & 7;          // batch -> XCD pin
    const int tile = blockIdx.x >> 3;
    const int i0   = tile * 64;

    const float* xb = x + (size_t)b * C_ * N_ + i0 + lane;
    #pragma unroll
    for (int cc = 0; cc < 8; ++cc) {
        const int chi = w * 8 + cc;
        float v[8];
        #pragma unroll
        for (int e = 0; e < 8; ++e) v[e] = xb[(size_t)(chi * 8 + e) * N_];
        unsigned short h[8];
        #pragma unroll
        for (int e = 0; e < 8; ++e) h[e] = f2bf(v[e]);
        *(uint4*)&S[(chi * 64 + lane) * 8] = pack8(h);
    }
    __syncthreads();

    f4_t acc[4][4];
    #pragma unroll
    for (int mt = 0; mt < 4; ++mt)
        #pragma unroll
        for (int nt = 0; nt < 4; ++nt) acc[mt][nt] = (f4_t)0.0f;
    f4_t qacc[2];
    qacc[0] = (f4_t)0.0f; qacc[1] = (f4_t)0.0f;

    #pragma unroll
    for (int kk = 0; kk < 8; ++kk) {
        bf8_t Bh[4];
        #pragma unroll
        for (int nt = 0; nt < 4; ++nt)
            Bh[nt] = *(const bf8_t*)&S[((kk * 4 + q4) * 64 + nt * 16 + l15) * 8];
        bf8_t Av[4];
        #pragma unroll
        for (int mt = 0; mt < 4; ++mt)
            Av[mt] = *(const bf8_t*)&wvF[(size_t)(((w * 4 + mt) * 8 + kk) * 64 + lane) * 8];
        bf8_t Aqh[2], Aql[2];
        #pragma unroll
        for (int mq = 0; mq < 2; ++mq) {
            Aqh[mq] = *(const bf8_t*)&wqFh[(size_t)((mq * 8 + kk) * 64 + lane) * 8];
            Aql[mq] = *(const bf8_t*)&wqFl[(size_t)((mq * 8 + kk) * 64 + lane) * 8];
        }

        #pragma unroll
        for (int mt = 0; mt < 4; ++mt)
            #pragma unroll
            for (int nt = 0; nt < 4; ++nt)
                acc[mt][nt] = __builtin_amdgcn_mfma_f32_16x16x32_bf16(
                    Av[mt], Bh[nt], acc[mt][nt], 0, 0, 0);
        #pragma unroll
        for (int mq = 0; mq < 2; ++mq) {
            qacc[mq] = __builtin_amdgcn_mfma_f32_16x16x32_bf16(Aqh[mq], Bh[w], qacc[mq], 0, 0, 0);
            qacc[mq] = __builtin_amdgcn_mfma_f32_16x16x32_bf16(Aql[mq], Bh[w], qacc[mq], 0, 0, 0);
        }
    }

    {
        const int iq = i0 + w * 16 + l15;
        #pragma unroll
        for (int mq = 0; mq < 2; ++mq) {
            float4 qb4 = *(const float4*)(qb + mq * 16 + q4 * 4);
            float qv[4] = {qacc[mq][0] + qb4.x, qacc[mq][1] + qb4.y,
                           qacc[mq][2] + qb4.z, qacc[mq][3] + qb4.w};
            unsigned short hr[4], lr[4];
            #pragma unroll
            for (int r = 0; r < 4; ++r) {
                hr[r] = f2bf(qv[r]);
                lr[r] = f2bf(qv[r] - bf2f(hr[r]));
            }
            uint2 uh, ul;
            uh.x = hr[0] | ((unsigned)hr[1] << 16); uh.y = hr[2] | ((unsigned)hr[3] << 16);
            ul.x = lr[0] | ((unsigned)lr[1] << 16); ul.y = lr[2] | ((unsigned)lr[3] << 16);
            size_t qoff = ((size_t)b * N_ + iq) * D_ + mq * 16 + q4 * 4;
            *(uint2*)(qh + qoff) = uh;
            *(uint2*)(ql + qoff) = ul;
        }
    }

    __syncthreads();
    #pragma unroll
    for (int mt = 0; mt < 4; ++mt) {
        float4 vb4 = *(const float4*)(vb + w * 64 + mt * 16 + q4 * 4);
        float bias[4] = {vb4.x, vb4.y, vb4.z, vb4.w};
        #pragma unroll
        for (int nt = 0; nt < 4; ++nt)
            #pragma unroll
            for (int r = 0; r < 4; ++r)
                S[(w * 64 + mt * 16 + q4 * 4 + r) * 72 + nt * 16 + l15] =
                    f2bf(acc[mt][nt][r] + bias[r]);
    }
    __syncthreads();
    // fragment-order global write: S[c=t][j-sub k2] -> vF[b][tile][k2][t][0..7]
    #pragma unroll
    for (int k2 = 0; k2 < 8; ++k2) {
        uint4 dat = *(const uint4*)&S[t * 72 + k2 * 8];
        *(uint4*)(vF + ((((size_t)b * 64 + tile) * 8 + k2) * 256 + t) * 8) = dat;
    }
}

// ---------------------------------------------------------------------------
// Kernel 2: MFMA flash attention, QBLK=64 (R1 base).
// R4 CHANGES:
//  (a) Vs LDS staging DELETED. B-fragments (V) load directly from global vF
//      (fragment-ordered by proj; 2MB/batch, XCD-pinned L2-resident).
//      R3 proved staging dominates: doubling it (QBLK 32) cost 1.7x.
//  (b) Pb transpose swizzled with PSWZ: scalar u16 writes were the real bank
//      conflict (8 banks x 8 lanes); reads stay uniform. (R1's pad attempt
//      provably changed nothing: conflict counter byte-identical.)
//  (c) LDS: union of Pb (8KB, loop) and T (17KB, epilogue) = 17.4KB total.
// ---------------------------------------------------------------------------
__global__ __launch_bounds__(256, 3) void attn_kernel(
    const unsigned short* __restrict__ qh, const unsigned short* __restrict__ ql,
    const unsigned short* __restrict__ vF, const float* __restrict__ x,
    const float* __restrict__ gamma_p, float* __restrict__ out)
{
    __shared__ __align__(16) unsigned char UB[17408];   // Pb (loop) / T (epilogue)
    __shared__ __align__(16) float rowl[64];
    unsigned short* Pb = (unsigned short*)UB;
    float* T = (float*)UB;

    const int t    = threadIdx.x;
    const int lane = t & 63;
    const int w    = t >> 6;
    const int q4   = lane >> 4;
    const int l15  = lane & 15;
    const int b    = blockIdx.x & 7;              // batch -> XCD pin
    const int i0   = (blockIdx.x >> 3) * 64;

    const unsigned short* qhb = qh + (size_t)b * N_ * D_;
    const unsigned short* qlb = ql + (size_t)b * N_ * D_;
    const unsigned short* vFb = vF + (size_t)b * 1048576;   // 64 tiles * 16384

    bf8_t Ah[4], Al[4];
    #pragma unroll
    for (int mt = 0; mt < 4; ++mt) {
        size_t off = (size_t)(i0 + mt * 16 + l15) * D_ + q4 * 8;
        Ah[mt] = *(const bf8_t*)(qhb + off);
        Al[mt] = *(const bf8_t*)(qlb + off);
    }

    f4_t acc[4][4];
    #pragma unroll
    for (int mt = 0; mt < 4; ++mt)
        #pragma unroll
        for (int nt = 0; nt < 4; ++nt) acc[mt][nt] = (f4_t)0.0f;

    f4_t lacc[4];
    #pragma unroll
    for (int mt = 0; mt < 4; ++mt) lacc[mt] = (f4_t)0.0f;
    bf8_t onesb;
    #pragma unroll
    for (int e = 0; e < 8; ++e) onesb[e] = (short)0x3F80;

    const int jl = w * 16 + l15;
    const int pprt = jl >> 3, jlo = jl & 7;

    for (int jt = 0; jt < N_ / 64; ++jt) {
        const int j0 = jt * 64;

        size_t koff = (size_t)(j0 + w * 16 + l15) * D_ + q4 * 8;
        bf8_t Bh = *(const bf8_t*)(qhb + koff);
        bf8_t Bl = *(const bf8_t*)(qlb + koff);

        f4_t s[4];
        #pragma unroll
        for (int mt = 0; mt < 4; ++mt) {
            f4_t a = (f4_t)0.0f;
            a = __builtin_amdgcn_mfma_f32_16x16x32_bf16(Ah[mt], Bh, a, 0, 0, 0);
            a = __builtin_amdgcn_mfma_f32_16x16x32_bf16(Ah[mt], Bl, a, 0, 0, 0);
            a = __builtin_amdgcn_mfma_f32_16x16x32_bf16(Al[mt], Bh, a, 0, 0, 0);
            s[mt] = a;
        }

        unsigned short pu[4][4];
        #pragma unroll
        for (int mt = 0; mt < 4; ++mt)
            #pragma unroll
            for (int r = 0; r < 4; ++r)
                pu[mt][r] = f2bf(__expf(s[mt][r] - FMX));

        __syncthreads();   // PV(jt-1) done reading Pb

        #pragma unroll
        for (int mt = 0; mt < 4; ++mt)
            #pragma unroll
            for (int r = 0; r < 4; ++r) {
                int u = pprt * 64 + mt * 16 + q4 * 4 + r;
                Pb[PSWZ(u) * 8 + jlo] = pu[mt][r];
            }

        __syncthreads();   // Pb(jt) visible

        const unsigned short* vj = vFb + (size_t)jt * 16384;
        #pragma unroll
        for (int kk = 0; kk < 2; ++kk) {
            bf8_t Af[4], Bf[4];
            #pragma unroll
            for (int nt = 0; nt < 4; ++nt)
                Bf[nt] = *(const bf8_t*)(vj +
                    (size_t)((kk * 4 + q4) * 256 + w * 64 + nt * 16 + l15) * 8);
            #pragma unroll
            for (int mt = 0; mt < 4; ++mt) {
                int u = (kk * 4 + q4) * 64 + mt * 16 + l15;
                Af[mt] = *(const bf8_t*)&Pb[PSWZ(u) * 8];
            }
            #pragma unroll
            for (int mt = 0; mt < 4; ++mt)
                #pragma unroll
                for (int nt = 0; nt < 4; ++nt)
                    acc[mt][nt] = __builtin_amdgcn_mfma_f32_16x16x32_bf16(
                        Af[mt], Bf[nt], acc[mt][nt], 0, 0, 0);
            if (w == 3) {
                #pragma unroll
                for (int mt = 0; mt < 4; ++mt)
                    lacc[mt] = __builtin_amdgcn_mfma_f32_16x16x32_bf16(
                        Af[mt], onesb, lacc[mt], 0, 0, 0);
            }
        }
    }

    __syncthreads();
    if (w == 3 && l15 == 0) {
        #pragma unroll
        for (int mt = 0; mt < 4; ++mt)
            #pragma unroll
            for (int r = 0; r < 4; ++r)
                rowl[mt * 16 + q4 * 4 + r] = lacc[mt][r];
    }
    __syncthreads();

    const float g = gamma_p[0];
    for (int mt = 0; mt < 4; ++mt) {
        float4 rl = *(float4*)(&rowl[mt * 16 + q4 * 4]);
        float inv[4] = { g / rl.x, g / rl.y, g / rl.z, g / rl.w };
        #pragma unroll
        for (int nt = 0; nt < 4; ++nt)
            #pragma unroll
            for (int r = 0; r < 4; ++r)
                T[(w * 64 + nt * 16 + l15) * 17 + q4 * 4 + r] = acc[mt][nt][r] * inv[r];
        __syncthreads();
        #pragma unroll
        for (int pass = 0; pass < 4; ++pass) {
            int c  = pass * 64 + (t >> 2);
            int ii = (t & 3) * 4;
            float4 o;
            o.x = T[c * 17 + ii];     o.y = T[c * 17 + ii + 1];
            o.z = T[c * 17 + ii + 2]; o.w = T[c * 17 + ii + 3];
            size_t goff = ((size_t)b * C_ + c) * N_ + i0 + mt * 16 + ii;
            float4 xv = *(const float4*)(x + goff);
            o.x += xv.x; o.y += xv.y; o.z += xv.z; o.w += xv.w;
            *(float4*)(out + goff) = o;
        }
        __syncthreads();
    }
}

extern "C" void kernel_launch(void* const* d_in, const int* in_sizes, int n_in,
                              void* d_out, int out_size, void* d_ws, size_t ws_size,
                              hipStream_t stream)
{
    const float* x     = (const float*)d_in[0];
    const float* q_w   = (const float*)d_in[1];
    const float* q_b   = (const float*)d_in[2];
    const float* v_w   = (const float*)d_in[3];
    const float* v_b   = (const float*)d_in[4];
    const float* gamma = (const float*)d_in[5];
    float* out = (float*)d_out;

    unsigned short* ws16 = (unsigned short*)d_ws;
    unsigned short* qhp  = ws16;                   // 1M u16
    unsigned short* qlp  = ws16 + 1048576;         // 1M u16
    unsigned short* vFp  = ws16 + 2097152;         // 8M u16 (fragment-order V)
    unsigned short* wvF  = ws16 + 10485760;        // 64K u16
    unsigned short* wqFh = wvF + 65536;            // 8K u16
    unsigned short* wqFl = wqFh + 8192;            // 8K u16

    wprep_kernel<<<36, 256, 0, stream>>>(q_w, v_w, wqFh, wqFl, wvF);
    proj_kernel<<<B_ * (N_ / 64), 256, 0, stream>>>(x, wqFh, wqFl, wvF, q_b, v_b,
                                                    qhp, qlp, vFp);
    attn_kernel<<<B_ * (N_ / 64), 256, 0, stream>>>(qhp, qlp, vFp, x, gamma, out);
}

// Round 5
// 227.879 us; speedup vs baseline: 1.8487x; 1.2378x over previous
//
#include <hip/hip_runtime.h>

#define B_   8
#define C_   256
#define D_   32
#define N_   4096
#define FMX  64.0f
// Pb XOR swizzle on the 16B-unit index (involution; read side stays uniform).
#define PSWZ(u) ((u) ^ (((u) >> 3) & 7))
// V LDS geometry: 8 p-blocks of 4KB + 16B pad -> q4 stride 4112B = 1028 dw = 4 mod 32
#define VP   4112
#define VBUF 32896   // 8 * 4112

typedef __attribute__((ext_vector_type(8))) short bf8_t;   // 8 bf16 (4 VGPRs)
typedef __attribute__((ext_vector_type(4))) float f4_t;    // MFMA C/D frag

__device__ __forceinline__ unsigned short f2bf(float f) {   // fp32 -> bf16 RNE
    unsigned int u = __builtin_bit_cast(unsigned int, f);
    u += 0x7FFFu + ((u >> 16) & 1u);
    return (unsigned short)(u >> 16);
}
__device__ __forceinline__ float bf2f(unsigned short h) {
    unsigned int u = ((unsigned int)h) << 16;
    return __builtin_bit_cast(float, u);
}
__device__ __forceinline__ uint4 pack8(const unsigned short* h) {
    uint4 u;
    u.x = h[0] | ((unsigned)h[1] << 16); u.y = h[2] | ((unsigned)h[3] << 16);
    u.z = h[4] | ((unsigned)h[5] << 16); u.w = h[6] | ((unsigned)h[7] << 16);
    return u;
}
__device__ __forceinline__ void gload_lds16(const void* g, void* l) {
    __builtin_amdgcn_global_load_lds(
        (const __attribute__((address_space(1))) unsigned int*)g,
        (__attribute__((address_space(3))) unsigned int*)l, 16, 0, 0);
}

// ---------------------------------------------------------------------------
// Kernel 0: weight prep -> A-fragment-ordered bf16 (unchanged).
// ---------------------------------------------------------------------------
__global__ __launch_bounds__(256) void wprep_kernel(
    const float* __restrict__ qw, const float* __restrict__ vw,
    unsigned short* __restrict__ wqFh, unsigned short* __restrict__ wqFl,
    unsigned short* __restrict__ wvF)
{
    const int tid = blockIdx.x * 256 + threadIdx.x;   // 36*256 = 9216
    if (tid < 8192) {
        const int k = tid;
        const int rowblk = k >> 9, kk = (k >> 6) & 7, lane = k & 63;
        const int oc = rowblk * 16 + (lane & 15), c0 = kk * 32 + (lane >> 4) * 8;
        const float* src = vw + oc * 256 + c0;
        unsigned short h[8];
        #pragma unroll
        for (int e = 0; e < 8; ++e) h[e] = f2bf(src[e]);
        *(uint4*)(wvF + (size_t)k * 8) = pack8(h);
    } else if (tid < 9216) {
        const int k = tid - 8192;
        const int rowblk = k >> 9, kk = (k >> 6) & 7, lane = k & 63;
        const int oc = rowblk * 16 + (lane & 15), c0 = kk * 32 + (lane >> 4) * 8;
        const float* src = qw + oc * 256 + c0;
        unsigned short h[8], l[8];
        #pragma unroll
        for (int e = 0; e < 8; ++e) {
            h[e] = f2bf(src[e]);
            l[e] = f2bf(src[e] - bf2f(h[e]));
        }
        *(uint4*)(wqFh + (size_t)k * 8) = pack8(h);
        *(uint4*)(wqFl + (size_t)k * 8) = pack8(l);
    }
}

// ---------------------------------------------------------------------------
// Kernel 1: MFMA projections (R4 verbatim: V written in MFMA-B-fragment order
// vF[b][tile][p][c][e] = V[c][tile*64 + p*8 + e]; 4KB-contiguous wave writes).
// ---------------------------------------------------------------------------
__global__ __launch_bounds__(256, 2) void proj_kernel(
    const float* __restrict__ x, const unsigned short* __restrict__ wqFh,
    const unsigned short* __restrict__ wqFl, const unsigned short* __restrict__ wvF,
    const float* __restrict__ qb, const float* __restrict__ vb,
    unsigned short* __restrict__ qh, unsigned short* __restrict__ ql,
    unsigned short* __restrict__ vF)
{
    __shared__ __align__(16) unsigned short S[18432];

    const int t    = threadIdx.x;
    const int lane = t & 63;
    const int w    = t >> 6;
    const int q4   = lane >> 4;
    const int l15  = lane & 15;
    const int b    = blockIdx.x & 7;          // batch -> XCD pin
    const int tile = blockIdx.x >> 3;
    const int i0   = tile * 64;

    const float* xb = x + (size_t)b * C_ * N_ + i0 + lane;
    #pragma unroll
    for (int cc = 0; cc < 8; ++cc) {
        const int chi = w * 8 + cc;
        float v[8];
        #pragma unroll
        for (int e = 0; e < 8; ++e) v[e] = xb[(size_t)(chi * 8 + e) * N_];
        unsigned short h[8];
        #pragma unroll
        for (int e = 0; e < 8; ++e) h[e] = f2bf(v[e]);
        *(uint4*)&S[(chi * 64 + lane) * 8] = pack8(h);
    }
    __syncthreads();

    f4_t acc[4][4];
    #pragma unroll
    for (int mt = 0; mt < 4; ++mt)
        #pragma unroll
        for (int nt = 0; nt < 4; ++nt) acc[mt][nt] = (f4_t)0.0f;
    f4_t qacc[2];
    qacc[0] = (f4_t)0.0f; qacc[1] = (f4_t)0.0f;

    #pragma unroll
    for (int kk = 0; kk < 8; ++kk) {
        bf8_t Bh[4];
        #pragma unroll
        for (int nt = 0; nt < 4; ++nt)
            Bh[nt] = *(const bf8_t*)&S[((kk * 4 + q4) * 64 + nt * 16 + l15) * 8];
        bf8_t Av[4];
        #pragma unroll
        for (int mt = 0; mt < 4; ++mt)
            Av[mt] = *(const bf8_t*)&wvF[(size_t)(((w * 4 + mt) * 8 + kk) * 64 + lane) * 8];
        bf8_t Aqh[2], Aql[2];
        #pragma unroll
        for (int mq = 0; mq < 2; ++mq) {
            Aqh[mq] = *(const bf8_t*)&wqFh[(size_t)((mq * 8 + kk) * 64 + lane) * 8];
            Aql[mq] = *(const bf8_t*)&wqFl[(size_t)((mq * 8 + kk) * 64 + lane) * 8];
        }

        #pragma unroll
        for (int mt = 0; mt < 4; ++mt)
            #pragma unroll
            for (int nt = 0; nt < 4; ++nt)
                acc[mt][nt] = __builtin_amdgcn_mfma_f32_16x16x32_bf16(
                    Av[mt], Bh[nt], acc[mt][nt], 0, 0, 0);
        #pragma unroll
        for (int mq = 0; mq < 2; ++mq) {
            qacc[mq] = __builtin_amdgcn_mfma_f32_16x16x32_bf16(Aqh[mq], Bh[w], qacc[mq], 0, 0, 0);
            qacc[mq] = __builtin_amdgcn_mfma_f32_16x16x32_bf16(Aql[mq], Bh[w], qacc[mq], 0, 0, 0);
        }
    }

    {
        const int iq = i0 + w * 16 + l15;
        #pragma unroll
        for (int mq = 0; mq < 2; ++mq) {
            float4 qb4 = *(const float4*)(qb + mq * 16 + q4 * 4);
            float qv[4] = {qacc[mq][0] + qb4.x, qacc[mq][1] + qb4.y,
                           qacc[mq][2] + qb4.z, qacc[mq][3] + qb4.w};
            unsigned short hr[4], lr[4];
            #pragma unroll
            for (int r = 0; r < 4; ++r) {
                hr[r] = f2bf(qv[r]);
                lr[r] = f2bf(qv[r] - bf2f(hr[r]));
            }
            uint2 uh, ul;
            uh.x = hr[0] | ((unsigned)hr[1] << 16); uh.y = hr[2] | ((unsigned)hr[3] << 16);
            ul.x = lr[0] | ((unsigned)lr[1] << 16); ul.y = lr[2] | ((unsigned)lr[3] << 16);
            size_t qoff = ((size_t)b * N_ + iq) * D_ + mq * 16 + q4 * 4;
            *(uint2*)(qh + qoff) = uh;
            *(uint2*)(ql + qoff) = ul;
        }
    }

    __syncthreads();
    #pragma unroll
    for (int mt = 0; mt < 4; ++mt) {
        float4 vb4 = *(const float4*)(vb + w * 64 + mt * 16 + q4 * 4);
        float bias[4] = {vb4.x, vb4.y, vb4.z, vb4.w};
        #pragma unroll
        for (int nt = 0; nt < 4; ++nt)
            #pragma unroll
            for (int r = 0; r < 4; ++r)
                S[(w * 64 + mt * 16 + q4 * 4 + r) * 72 + nt * 16 + l15] =
                    f2bf(acc[mt][nt][r] + bias[r]);
    }
    __syncthreads();
    #pragma unroll
    for (int k2 = 0; k2 < 8; ++k2) {
        uint4 dat = *(const uint4*)&S[t * 72 + k2 * 8];
        *(uint4*)(vF + ((((size_t)b * 64 + tile) * 8 + k2) * 256 + t) * 8) = dat;
    }
}

// ---------------------------------------------------------------------------
// Kernel 2: MFMA flash attention.
// R5: back to LDS-staged V (R1's winning regime) but staged via
// global_load_lds width-16 DMA from the fragment-ordered vF:
//  - no VGPR round-trip, no ds_write instrs (R1's staging cost),
//  - double-buffered; STAGE(jt+1) issued after barrier2 so the DMA overlaps
//    PV(jt)+QK(jt+1)+exp before barrier1(jt+1)'s implicit vmcnt(0) drain,
//  - K(jt+1) loads issued BEFORE STAGE(jt+1): vmcnt is ordered, so QK's wait
//    becomes vmcnt(8) (stage still in flight) instead of vmcnt(0),
//  - 16B pad per 4KB p-block reproduces R1's conflict-free q4 stride
//    (4112B = 1028 dw = 4 mod 32),
//  - PSWZ'd Pb kept (8.9M -> 4.7M conflict cycles measured).
// ---------------------------------------------------------------------------
__global__ __launch_bounds__(256, 2) void attn_kernel(
    const unsigned short* __restrict__ qh, const unsigned short* __restrict__ ql,
    const unsigned short* __restrict__ vF, const float* __restrict__ x,
    const float* __restrict__ gamma_p, float* __restrict__ out)
{
    __shared__ __align__(16) unsigned char SMEM[2 * VBUF];   // V dbuf / epilogue T
    __shared__ __align__(16) unsigned short Pb[4096];        // swizzled P (8KB)
    __shared__ __align__(16) float rowl[64];
    float* T = (float*)SMEM;

    const int t    = threadIdx.x;
    const int lane = t & 63;
    const int w    = t >> 6;
    const int q4   = lane >> 4;
    const int l15  = lane & 15;
    const int b    = blockIdx.x & 7;              // batch -> XCD pin
    const int i0   = (blockIdx.x >> 3) * 64;

    const unsigned short* qhb = qh + (size_t)b * N_ * D_;
    const unsigned short* qlb = ql + (size_t)b * N_ * D_;
    const unsigned short* vFb = vF + (size_t)b * 1048576;   // 64 tiles * 16384 u16

    // A-fragments (resident all loop)
    bf8_t Ah[4], Al[4];
    #pragma unroll
    for (int mt = 0; mt < 4; ++mt) {
        size_t off = (size_t)(i0 + mt * 16 + l15) * D_ + q4 * 8;
        Ah[mt] = *(const bf8_t*)(qhb + off);
        Al[mt] = *(const bf8_t*)(qlb + off);
    }

    // DMA-stage tile jt into buffer buf: 32 chunks of 1KB, 8 per wave.
    auto STAGE = [&](int jt, int buf) {
        const unsigned short* vj = vFb + (size_t)jt * 16384;
        #pragma unroll
        for (int i = 0; i < 8; ++i) {
            const int c = i * 4 + w;              // chunk id, wave-uniform
            const int p = c >> 2, sub = c & 3;
            gload_lds16(vj + c * 512 + lane * 8,
                        &SMEM[buf * VBUF + p * VP + sub * 1024]);
        }
    };

    f4_t acc[4][4];
    #pragma unroll
    for (int mt = 0; mt < 4; ++mt)
        #pragma unroll
        for (int nt = 0; nt < 4; ++nt) acc[mt][nt] = (f4_t)0.0f;

    f4_t lacc[4];
    #pragma unroll
    for (int mt = 0; mt < 4; ++mt) lacc[mt] = (f4_t)0.0f;
    bf8_t onesb;
    #pragma unroll
    for (int e = 0; e < 8; ++e) onesb[e] = (short)0x3F80;

    const int jl = w * 16 + l15;
    const int pprt = jl >> 3, jlo = jl & 7;

    // prologue: K(0) first (so its wait is vmcnt(8)), then stage tile 0
    size_t koff0 = (size_t)(0 + w * 16 + l15) * D_ + q4 * 8;
    bf8_t Bh = *(const bf8_t*)(qhb + koff0);
    bf8_t Bl = *(const bf8_t*)(qlb + koff0);
    STAGE(0, 0);

    for (int jt = 0; jt < N_ / 64; ++jt) {
        const int cur = jt & 1;

        // QK: needs A-frags + K regs -> vmcnt(8); stage(jt) still in flight
        f4_t s[4];
        #pragma unroll
        for (int mt = 0; mt < 4; ++mt) {
            f4_t a = (f4_t)0.0f;
            a = __builtin_amdgcn_mfma_f32_16x16x32_bf16(Ah[mt], Bh, a, 0, 0, 0);
            a = __builtin_amdgcn_mfma_f32_16x16x32_bf16(Ah[mt], Bl, a, 0, 0, 0);
            a = __builtin_amdgcn_mfma_f32_16x16x32_bf16(Al[mt], Bh, a, 0, 0, 0);
            s[mt] = a;
        }

        unsigned short pu[4][4];
        #pragma unroll
        for (int mt = 0; mt < 4; ++mt)
            #pragma unroll
            for (int r = 0; r < 4; ++r)
                pu[mt][r] = f2bf(__expf(s[mt][r] - FMX));

        __syncthreads();   // barrier1: Af(jt-1) reads done; drains stage(jt) DMA

        #pragma unroll
        for (int mt = 0; mt < 4; ++mt)
            #pragma unroll
            for (int r = 0; r < 4; ++r) {
                int u = pprt * 64 + mt * 16 + q4 * 4 + r;
                Pb[PSWZ(u) * 8 + jlo] = pu[mt][r];
            }

        __syncthreads();   // barrier2: Pb(jt) + Vs[cur] visible

        // issue K(jt+1) then DMA-stage tile jt+1 into the other buffer;
        // safe: buf[cur^1] was last read in PV(jt-1), before barrier1(jt).
        const int jn = (jt + 1 < N_ / 64) ? jt + 1 : jt;
        size_t koffn = (size_t)(jn * 64 + w * 16 + l15) * D_ + q4 * 8;
        bf8_t Bh_n = *(const bf8_t*)(qhb + koffn);
        bf8_t Bl_n = *(const bf8_t*)(qlb + koffn);
        if (jt + 1 < N_ / 64) STAGE(jt + 1, cur ^ 1);

        #pragma unroll
        for (int kk = 0; kk < 2; ++kk) {
            bf8_t Af[4], Bf[4];
            #pragma unroll
            for (int nt = 0; nt < 4; ++nt)
                Bf[nt] = *(const bf8_t*)&SMEM[cur * VBUF + (kk * 4 + q4) * VP +
                                              (w * 64 + nt * 16 + l15) * 16];
            #pragma unroll
            for (int mt = 0; mt < 4; ++mt) {
                int u = (kk * 4 + q4) * 64 + mt * 16 + l15;
                Af[mt] = *(const bf8_t*)&Pb[PSWZ(u) * 8];
            }
            #pragma unroll
            for (int mt = 0; mt < 4; ++mt)
                #pragma unroll
                for (int nt = 0; nt < 4; ++nt)
                    acc[mt][nt] = __builtin_amdgcn_mfma_f32_16x16x32_bf16(
                        Af[mt], Bf[nt], acc[mt][nt], 0, 0, 0);
            if (w == 3) {
                #pragma unroll
                for (int mt = 0; mt < 4; ++mt)
                    lacc[mt] = __builtin_amdgcn_mfma_f32_16x16x32_bf16(
                        Af[mt], onesb, lacc[mt], 0, 0, 0);
            }
        }

        Bh = Bh_n; Bl = Bl_n;
    }

    __syncthreads();
    if (w == 3 && l15 == 0) {
        #pragma unroll
        for (int mt = 0; mt < 4; ++mt)
            #pragma unroll
            for (int r = 0; r < 4; ++r)
                rowl[mt * 16 + q4 * 4 + r] = lacc[mt][r];
    }
    __syncthreads();

    const float g = gamma_p[0];
    for (int mt = 0; mt < 4; ++mt) {
        float4 rl = *(float4*)(&rowl[mt * 16 + q4 * 4]);
        float inv[4] = { g / rl.x, g / rl.y, g / rl.z, g / rl.w };
        #pragma unroll
        for (int nt = 0; nt < 4; ++nt)
            #pragma unroll
            for (int r = 0; r < 4; ++r)
                T[(w * 64 + nt * 16 + l15) * 17 + q4 * 4 + r] = acc[mt][nt][r] * inv[r];
        __syncthreads();
        #pragma unroll
        for (int pass = 0; pass < 4; ++pass) {
            int c  = pass * 64 + (t >> 2);
            int ii = (t & 3) * 4;
            float4 o;
            o.x = T[c * 17 + ii];     o.y = T[c * 17 + ii + 1];
            o.z = T[c * 17 + ii + 2]; o.w = T[c * 17 + ii + 3];
            size_t goff = ((size_t)b * C_ + c) * N_ + i0 + mt * 16 + ii;
            float4 xv = *(const float4*)(x + goff);
            o.x += xv.x; o.y += xv.y; o.z += xv.z; o.w += xv.w;
            *(float4*)(out + goff) = o;
        }
        __syncthreads();
    }
}

extern "C" void kernel_launch(void* const* d_in, const int* in_sizes, int n_in,
                              void* d_out, int out_size, void* d_ws, size_t ws_size,
                              hipStream_t stream)
{
    const float* x     = (const float*)d_in[0];
    const float* q_w   = (const float*)d_in[1];
    const float* q_b   = (const float*)d_in[2];
    const float* v_w   = (const float*)d_in[3];
    const float* v_b   = (const float*)d_in[4];
    const float* gamma = (const float*)d_in[5];
    float* out = (float*)d_out;

    unsigned short* ws16 = (unsigned short*)d_ws;
    unsigned short* qhp  = ws16;                   // 1M u16
    unsigned short* qlp  = ws16 + 1048576;         // 1M u16
    unsigned short* vFp  = ws16 + 2097152;         // 8M u16 (fragment-order V)
    unsigned short* wvF  = ws16 + 10485760;        // 64K u16
    unsigned short* wqFh = wvF + 65536;            // 8K u16
    unsigned short* wqFl = wqFh + 8192;            // 8K u16

    wprep_kernel<<<36, 256, 0, stream>>>(q_w, v_w, wqFh, wqFl, wvF);
    proj_kernel<<<B_ * (N_ / 64), 256, 0, stream>>>(x, wqFh, wqFl, wvF, q_b, v_b,
                                                    qhp, qlp, vFp);
    attn_kernel<<<B_ * (N_ / 64), 256, 0, stream>>>(qhp, qlp, vFp, x, gamma, out);
}

// Round 6
// 225.911 us; speedup vs baseline: 1.8648x; 1.0087x over previous
//
#include <hip/hip_runtime.h>

#define B_   8
#define C_   256
#define D_   32
#define N_   4096
#define FMX  64.0f
// Pb XOR swizzle on the 16B-unit index (involution; read side stays uniform).
#define PSWZ(u) ((u) ^ (((u) >> 3) & 7))
#define VBUF 32768   // one V tile: 8 p-blocks * 256 ch * 16B, linear (no pads)

typedef __attribute__((ext_vector_type(8))) short bf8_t;   // 8 bf16 (4 VGPRs)
typedef __attribute__((ext_vector_type(4))) float f4_t;    // MFMA C/D frag

__device__ __forceinline__ unsigned short f2bf(float f) {   // fp32 -> bf16 RNE
    unsigned int u = __builtin_bit_cast(unsigned int, f);
    u += 0x7FFFu + ((u >> 16) & 1u);
    return (unsigned short)(u >> 16);
}
__device__ __forceinline__ float bf2f(unsigned short h) {
    unsigned int u = ((unsigned int)h) << 16;
    return __builtin_bit_cast(float, u);
}
__device__ __forceinline__ uint4 pack8(const unsigned short* h) {
    uint4 u;
    u.x = h[0] | ((unsigned)h[1] << 16); u.y = h[2] | ((unsigned)h[3] << 16);
    u.z = h[4] | ((unsigned)h[5] << 16); u.w = h[6] | ((unsigned)h[7] << 16);
    return u;
}
__device__ __forceinline__ void gload_lds16(const void* g, void* l) {
    __builtin_amdgcn_global_load_lds(
        (const __attribute__((address_space(1))) unsigned int*)g,
        (__attribute__((address_space(3))) unsigned int*)l, 16, 0, 0);
}

// ---------------------------------------------------------------------------
// Kernel 0: weight prep -> A-fragment-ordered bf16 (unchanged).
// ---------------------------------------------------------------------------
__global__ __launch_bounds__(256) void wprep_kernel(
    const float* __restrict__ qw, const float* __restrict__ vw,
    unsigned short* __restrict__ wqFh, unsigned short* __restrict__ wqFl,
    unsigned short* __restrict__ wvF)
{
    const int tid = blockIdx.x * 256 + threadIdx.x;   // 36*256 = 9216
    if (tid < 8192) {
        const int k = tid;
        const int rowblk = k >> 9, kk = (k >> 6) & 7, lane = k & 63;
        const int oc = rowblk * 16 + (lane & 15), c0 = kk * 32 + (lane >> 4) * 8;
        const float* src = vw + oc * 256 + c0;
        unsigned short h[8];
        #pragma unroll
        for (int e = 0; e < 8; ++e) h[e] = f2bf(src[e]);
        *(uint4*)(wvF + (size_t)k * 8) = pack8(h);
    } else if (tid < 9216) {
        const int k = tid - 8192;
        const int rowblk = k >> 9, kk = (k >> 6) & 7, lane = k & 63;
        const int oc = rowblk * 16 + (lane & 15), c0 = kk * 32 + (lane >> 4) * 8;
        const float* src = qw + oc * 256 + c0;
        unsigned short h[8], l[8];
        #pragma unroll
        for (int e = 0; e < 8; ++e) {
            h[e] = f2bf(src[e]);
            l[e] = f2bf(src[e] - bf2f(h[e]));
        }
        *(uint4*)(wqFh + (size_t)k * 8) = pack8(h);
        *(uint4*)(wqFl + (size_t)k * 8) = pack8(l);
    }
}

// ---------------------------------------------------------------------------
// Kernel 1: MFMA projections.
// R6: n-tile 32 (was 64) -> grid 1024 = 4 blocks/CU (volume-neutral: each
// block reads its own disjoint x slab; x HBM total unchanged). acc halves
// to 32 VGPR. S staging gets an n^(chi&3) XOR swizzle (Bh reads had a 4-way
// q4 conflict at any power-of-2 group stride). V epilogue writes vF with
// channel position c^(p&3) so attn's linear-DMA'd LDS reads are bank-even.
// ---------------------------------------------------------------------------
__global__ __launch_bounds__(256, 4) void proj_kernel(
    const float* __restrict__ x, const unsigned short* __restrict__ wqFh,
    const unsigned short* __restrict__ wqFl, const unsigned short* __restrict__ wvF,
    const float* __restrict__ qb, const float* __restrict__ vb,
    unsigned short* __restrict__ qh, unsigned short* __restrict__ ql,
    unsigned short* __restrict__ vF)
{
    __shared__ __align__(16) unsigned short S[10240];   // stage 8K u16 / epi 256*40

    const int t    = threadIdx.x;
    const int lane = t & 63;
    const int w    = t >> 6;
    const int q4   = lane >> 4;
    const int l15  = lane & 15;
    const int b    = blockIdx.x & 7;          // batch -> XCD pin
    const int tt   = blockIdx.x >> 3;         // 0..127, n-tile of 32
    const int i0   = tt * 32;

    // stage x tile [256 ch][32 n] -> S[chi 32][n^ (chi&3)][8 ch-sub] bf16
    {
        const int n  = lane & 31;
        const int hi = lane >> 5;
        const float* xb = x + (size_t)b * C_ * N_ + i0 + n;
        #pragma unroll
        for (int cc = 0; cc < 4; ++cc) {
            const int chi = w * 8 + cc * 2 + hi;
            float v[8];
            #pragma unroll
            for (int e = 0; e < 8; ++e) v[e] = xb[(size_t)(chi * 8 + e) * N_];
            unsigned short h[8];
            #pragma unroll
            for (int e = 0; e < 8; ++e) h[e] = f2bf(v[e]);
            *(uint4*)&S[(chi * 32 + (n ^ (chi & 3))) * 8] = pack8(h);
        }
    }
    __syncthreads();

    f4_t acc[4][2];
    #pragma unroll
    for (int mt = 0; mt < 4; ++mt)
        #pragma unroll
        for (int nt = 0; nt < 2; ++nt) acc[mt][nt] = (f4_t)0.0f;
    f4_t qacc[2];
    qacc[0] = (f4_t)0.0f; qacc[1] = (f4_t)0.0f;

    #pragma unroll
    for (int kk = 0; kk < 8; ++kk) {
        bf8_t Bh[2];
        #pragma unroll
        for (int nt = 0; nt < 2; ++nt)
            Bh[nt] = *(const bf8_t*)&S[((kk * 4 + q4) * 32 + nt * 16 + (l15 ^ q4)) * 8];
        bf8_t Av[4];
        #pragma unroll
        for (int mt = 0; mt < 4; ++mt)
            Av[mt] = *(const bf8_t*)&wvF[(size_t)(((w * 4 + mt) * 8 + kk) * 64 + lane) * 8];

        #pragma unroll
        for (int mt = 0; mt < 4; ++mt)
            #pragma unroll
            for (int nt = 0; nt < 2; ++nt)
                acc[mt][nt] = __builtin_amdgcn_mfma_f32_16x16x32_bf16(
                    Av[mt], Bh[nt], acc[mt][nt], 0, 0, 0);

        if (w < 2) {   // q projection: n-tiles 0,1 handled by waves 0,1
            #pragma unroll
            for (int mq = 0; mq < 2; ++mq) {
                bf8_t Aqh = *(const bf8_t*)&wqFh[(size_t)((mq * 8 + kk) * 64 + lane) * 8];
                bf8_t Aql = *(const bf8_t*)&wqFl[(size_t)((mq * 8 + kk) * 64 + lane) * 8];
                qacc[mq] = __builtin_amdgcn_mfma_f32_16x16x32_bf16(Aqh, Bh[w], qacc[mq], 0, 0, 0);
                qacc[mq] = __builtin_amdgcn_mfma_f32_16x16x32_bf16(Aql, Bh[w], qacc[mq], 0, 0, 0);
            }
        }
    }

    if (w < 2) {
        const int iq = i0 + w * 16 + l15;
        #pragma unroll
        for (int mq = 0; mq < 2; ++mq) {
            float4 qb4 = *(const float4*)(qb + mq * 16 + q4 * 4);
            float qv[4] = {qacc[mq][0] + qb4.x, qacc[mq][1] + qb4.y,
                           qacc[mq][2] + qb4.z, qacc[mq][3] + qb4.w};
            unsigned short hr[4], lr[4];
            #pragma unroll
            for (int r = 0; r < 4; ++r) {
                hr[r] = f2bf(qv[r]);
                lr[r] = f2bf(qv[r] - bf2f(hr[r]));
            }
            uint2 uh, ul;
            uh.x = hr[0] | ((unsigned)hr[1] << 16); uh.y = hr[2] | ((unsigned)hr[3] << 16);
            ul.x = lr[0] | ((unsigned)lr[1] << 16); ul.y = lr[2] | ((unsigned)lr[3] << 16);
            size_t qoff = ((size_t)b * N_ + iq) * D_ + mq * 16 + q4 * 4;
            *(uint2*)(qh + qoff) = uh;
            *(uint2*)(ql + qoff) = ul;
        }
    }

    __syncthreads();
    #pragma unroll
    for (int mt = 0; mt < 4; ++mt) {
        float4 vb4 = *(const float4*)(vb + w * 64 + mt * 16 + q4 * 4);
        float bias[4] = {vb4.x, vb4.y, vb4.z, vb4.w};
        #pragma unroll
        for (int nt = 0; nt < 2; ++nt)
            #pragma unroll
            for (int r = 0; r < 4; ++r)
                S[(w * 64 + mt * 16 + q4 * 4 + r) * 40 + nt * 16 + l15] =
                    f2bf(acc[mt][nt][r] + bias[r]);
    }
    __syncthreads();
    // fragment-order global write with channel swizzle: position c^(p&3).
    #pragma unroll
    for (int k2 = 0; k2 < 4; ++k2) {
        int id  = k2 * 256 + t;
        int oc  = id >> 2, seg = id & 3;          // seg: n-sub of 8 within 32
        uint4 dat = *(const uint4*)&S[oc * 40 + seg * 8];
        size_t p  = (size_t)(tt & 1) * 4 + seg;   // p-block within 64-tile
        size_t off = ((((size_t)b * 64 + (tt >> 1)) * 8 + p) * 256 + (oc ^ seg)) * 8;
        *(uint4*)(vF + off) = dat;
    }
}

// ---------------------------------------------------------------------------
// Kernel 2: MFMA flash attention.
// R6 (from R5's 131us): ONE barrier per jt (Pb double-buffered; Pb[cur]'s
// last reader PV(jt-2) is fenced by barrier(jt-1)). V LDS linear (VP=4096,
// fits 2 blocks at exactly 80KB/block); V bank spread now comes from the
// vF content swizzle (c^q4) instead of pads. T5 setprio around PV cluster.
// ---------------------------------------------------------------------------
__global__ __launch_bounds__(256, 2) void attn_kernel(
    const unsigned short* __restrict__ qh, const unsigned short* __restrict__ ql,
    const unsigned short* __restrict__ vF, const float* __restrict__ x,
    const float* __restrict__ gamma_p, float* __restrict__ out)
{
    __shared__ __align__(16) unsigned char SMEM[2 * VBUF];   // V dbuf / epilogue T
    __shared__ __align__(16) unsigned short Pb[2][4096];     // P dbuf (swizzled)
    float* T    = (float*)SMEM;
    float* rowl = (float*)&Pb[0][0];                         // epilogue alias

    const int t    = threadIdx.x;
    const int lane = t & 63;
    const int w    = t >> 6;
    const int q4   = lane >> 4;
    const int l15  = lane & 15;
    const int b    = blockIdx.x & 7;              // batch -> XCD pin
    const int i0   = (blockIdx.x >> 3) * 64;

    const unsigned short* qhb = qh + (size_t)b * N_ * D_;
    const unsigned short* qlb = ql + (size_t)b * N_ * D_;
    const unsigned short* vFb = vF + (size_t)b * 1048576;   // 64 tiles * 16384 u16

    bf8_t Ah[4], Al[4];
    #pragma unroll
    for (int mt = 0; mt < 4; ++mt) {
        size_t off = (size_t)(i0 + mt * 16 + l15) * D_ + q4 * 8;
        Ah[mt] = *(const bf8_t*)(qhb + off);
        Al[mt] = *(const bf8_t*)(qlb + off);
    }

    // DMA-stage tile jt: 32 chunks of 1KB, 8 per wave; LDS dest linear.
    auto STAGE = [&](int jt, int buf) {
        const unsigned short* vj = vFb + (size_t)jt * 16384;
        #pragma unroll
        for (int i = 0; i < 8; ++i) {
            const int c = i * 4 + w;              // chunk id, wave-uniform
            gload_lds16(vj + c * 512 + lane * 8, &SMEM[buf * VBUF + c * 1024]);
        }
    };

    f4_t acc[4][4];
    #pragma unroll
    for (int mt = 0; mt < 4; ++mt)
        #pragma unroll
        for (int nt = 0; nt < 4; ++nt) acc[mt][nt] = (f4_t)0.0f;

    f4_t lacc[4];
    #pragma unroll
    for (int mt = 0; mt < 4; ++mt) lacc[mt] = (f4_t)0.0f;
    bf8_t onesb;
    #pragma unroll
    for (int e = 0; e < 8; ++e) onesb[e] = (short)0x3F80;

    const int jl = w * 16 + l15;
    const int pprt = jl >> 3, jlo = jl & 7;

    // prologue: K(0) first (so QK waits vmcnt(8), not 0), then stage tile 0
    size_t koff0 = (size_t)(w * 16 + l15) * D_ + q4 * 8;
    bf8_t Bh = *(const bf8_t*)(qhb + koff0);
    bf8_t Bl = *(const bf8_t*)(qlb + koff0);
    STAGE(0, 0);

    for (int jt = 0; jt < N_ / 64; ++jt) {
        const int cur = jt & 1;

        f4_t s[4];
        #pragma unroll
        for (int mt = 0; mt < 4; ++mt) {
            f4_t a = (f4_t)0.0f;
            a = __builtin_amdgcn_mfma_f32_16x16x32_bf16(Ah[mt], Bh, a, 0, 0, 0);
            a = __builtin_amdgcn_mfma_f32_16x16x32_bf16(Ah[mt], Bl, a, 0, 0, 0);
            a = __builtin_amdgcn_mfma_f32_16x16x32_bf16(Al[mt], Bh, a, 0, 0, 0);
            s[mt] = a;
        }

        unsigned short pu[4][4];
        #pragma unroll
        for (int mt = 0; mt < 4; ++mt)
            #pragma unroll
            for (int r = 0; r < 4; ++r)
                pu[mt][r] = f2bf(__expf(s[mt][r] - FMX));

        // write P(jt) into Pb[cur]: last readers (PV(jt-2)) fenced by barrier(jt-1)
        #pragma unroll
        for (int mt = 0; mt < 4; ++mt)
            #pragma unroll
            for (int r = 0; r < 4; ++r) {
                int u = pprt * 64 + mt * 16 + q4 * 4 + r;
                Pb[cur][PSWZ(u) * 8 + jlo] = pu[mt][r];
            }

        __syncthreads();   // SINGLE barrier: Pb[cur] visible + STAGE(jt) drained

        // post-barrier: K(jt+1) then STAGE(jt+1) into the other buffer
        // (V[cur^1] last read PV(jt-1), fenced by this barrier)
        const int jn = (jt + 1 < N_ / 64) ? jt + 1 : jt;
        size_t koffn = (size_t)(jn * 64 + w * 16 + l15) * D_ + q4 * 8;
        bf8_t Bh_n = *(const bf8_t*)(qhb + koffn);
        bf8_t Bl_n = *(const bf8_t*)(qlb + koffn);
        if (jt + 1 < N_ / 64) STAGE(jt + 1, cur ^ 1);

        __builtin_amdgcn_s_setprio(1);
        #pragma unroll
        for (int kk = 0; kk < 2; ++kk) {
            bf8_t Af[4], Bf[4];
            #pragma unroll
            for (int nt = 0; nt < 4; ++nt)
                Bf[nt] = *(const bf8_t*)&SMEM[cur * VBUF + (kk * 4 + q4) * 4096 +
                                              ((w * 64 + nt * 16 + l15) ^ q4) * 16];
            #pragma unroll
            for (int mt = 0; mt < 4; ++mt) {
                int u = (kk * 4 + q4) * 64 + mt * 16 + l15;
                Af[mt] = *(const bf8_t*)&Pb[cur][PSWZ(u) * 8];
            }
            #pragma unroll
            for (int mt = 0; mt < 4; ++mt)
                #pragma unroll
                for (int nt = 0; nt < 4; ++nt)
                    acc[mt][nt] = __builtin_amdgcn_mfma_f32_16x16x32_bf16(
                        Af[mt], Bf[nt], acc[mt][nt], 0, 0, 0);
            if (w == 3) {
                #pragma unroll
                for (int mt = 0; mt < 4; ++mt)
                    lacc[mt] = __builtin_amdgcn_mfma_f32_16x16x32_bf16(
                        Af[mt], onesb, lacc[mt], 0, 0, 0);
            }
        }
        __builtin_amdgcn_s_setprio(0);

        Bh = Bh_n; Bl = Bl_n;
    }

    __syncthreads();
    if (w == 3 && l15 == 0) {
        #pragma unroll
        for (int mt = 0; mt < 4; ++mt)
            #pragma unroll
            for (int r = 0; r < 4; ++r)
                rowl[mt * 16 + q4 * 4 + r] = lacc[mt][r];
    }
    __syncthreads();

    const float g = gamma_p[0];
    for (int mt = 0; mt < 4; ++mt) {
        float4 rl = *(float4*)(&rowl[mt * 16 + q4 * 4]);
        float inv[4] = { g / rl.x, g / rl.y, g / rl.z, g / rl.w };
        #pragma unroll
        for (int nt = 0; nt < 4; ++nt)
            #pragma unroll
            for (int r = 0; r < 4; ++r)
                T[(w * 64 + nt * 16 + l15) * 17 + q4 * 4 + r] = acc[mt][nt][r] * inv[r];
        __syncthreads();
        #pragma unroll
        for (int pass = 0; pass < 4; ++pass) {
            int c  = pass * 64 + (t >> 2);
            int ii = (t & 3) * 4;
            float4 o;
            o.x = T[c * 17 + ii];     o.y = T[c * 17 + ii + 1];
            o.z = T[c * 17 + ii + 2]; o.w = T[c * 17 + ii + 3];
            size_t goff = ((size_t)b * C_ + c) * N_ + i0 + mt * 16 + ii;
            float4 xv = *(const float4*)(x + goff);
            o.x += xv.x; o.y += xv.y; o.z += xv.z; o.w += xv.w;
            *(float4*)(out + goff) = o;
        }
        __syncthreads();
    }
}

extern "C" void kernel_launch(void* const* d_in, const int* in_sizes, int n_in,
                              void* d_out, int out_size, void* d_ws, size_t ws_size,
                              hipStream_t stream)
{
    const float* x     = (const float*)d_in[0];
    const float* q_w   = (const float*)d_in[1];
    const float* q_b   = (const float*)d_in[2];
    const float* v_w   = (const float*)d_in[3];
    const float* v_b   = (const float*)d_in[4];
    const float* gamma = (const float*)d_in[5];
    float* out = (float*)d_out;

    unsigned short* ws16 = (unsigned short*)d_ws;
    unsigned short* qhp  = ws16;                   // 1M u16
    unsigned short* qlp  = ws16 + 1048576;         // 1M u16
    unsigned short* vFp  = ws16 + 2097152;         // 8M u16 (fragment-order V, c^p swizzled)
    unsigned short* wvF  = ws16 + 10485760;        // 64K u16
    unsigned short* wqFh = wvF + 65536;            // 8K u16
    unsigned short* wqFl = wqFh + 8192;            // 8K u16

    wprep_kernel<<<36, 256, 0, stream>>>(q_w, v_w, wqFh, wqFl, wvF);
    proj_kernel<<<B_ * (N_ / 32), 256, 0, stream>>>(x, wqFh, wqFl, wvF, q_b, v_b,
                                                    qhp, qlp, vFp);
    attn_kernel<<<B_ * (N_ / 64), 256, 0, stream>>>(qhp, qlp, vFp, x, gamma, out);
}

// Round 9
// 217.305 us; speedup vs baseline: 1.9387x; 1.0396x over previous
//
#include <hip/hip_runtime.h>

#define B_   8
#define C_   256
#define D_   32
#define N_   4096
#define FMX  64.0f
// P swizzle on the 16B-unit index. Includes BOTH (u>>3) and (u>>6) so that
// the write side's pprt (bits 6+) and the read side's q4 reach the bank bits.
// Bijective (low-3 bits XORed with a function of higher bits).
#define PSWZ2(u) ((u) ^ (((u) >> 3) & 7) ^ ((((u) >> 6) & 3) << 1))
#define VBUF 32768   // one V tile: 8 p-blocks * 256 ch * 16B, linear

typedef __attribute__((ext_vector_type(8))) short bf8_t;   // 8 bf16 (4 VGPRs)
typedef __attribute__((ext_vector_type(4))) float f4_t;    // MFMA C/D frag

__device__ __forceinline__ unsigned short f2bf(float f) {   // fp32 -> bf16 RNE
    unsigned int u = __builtin_bit_cast(unsigned int, f);
    u += 0x7FFFu + ((u >> 16) & 1u);
    return (unsigned short)(u >> 16);
}
__device__ __forceinline__ float bf2f(unsigned short h) {
    unsigned int u = ((unsigned int)h) << 16;
    return __builtin_bit_cast(float, u);
}
__device__ __forceinline__ uint4 pack8(const unsigned short* h) {
    uint4 u;
    u.x = h[0] | ((unsigned)h[1] << 16); u.y = h[2] | ((unsigned)h[3] << 16);
    u.z = h[4] | ((unsigned)h[5] << 16); u.w = h[6] | ((unsigned)h[7] << 16);
    return u;
}
__device__ __forceinline__ void gload_lds16(const void* g, void* l) {
    __builtin_amdgcn_global_load_lds(
        (const __attribute__((address_space(1))) unsigned int*)g,
        (__attribute__((address_space(3))) unsigned int*)l, 16, 0, 0);
}

struct IC0 { static constexpr int v = 0; };
struct IC1 { static constexpr int v = 1; };

// ---------------------------------------------------------------------------
// Kernel 0: weight prep -> A-fragment-ordered bf16 (unchanged).
// ---------------------------------------------------------------------------
__global__ __launch_bounds__(256) void wprep_kernel(
    const float* __restrict__ qw, const float* __restrict__ vw,
    unsigned short* __restrict__ wqFh, unsigned short* __restrict__ wqFl,
    unsigned short* __restrict__ wvF)
{
    const int tid = blockIdx.x * 256 + threadIdx.x;   // 36*256 = 9216
    if (tid < 8192) {
        const int k = tid;
        const int rowblk = k >> 9, kk = (k >> 6) & 7, lane = k & 63;
        const int oc = rowblk * 16 + (lane & 15), c0 = kk * 32 + (lane >> 4) * 8;
        const float* src = vw + oc * 256 + c0;
        unsigned short h[8];
        #pragma unroll
        for (int e = 0; e < 8; ++e) h[e] = f2bf(src[e]);
        *(uint4*)(wvF + (size_t)k * 8) = pack8(h);
    } else if (tid < 9216) {
        const int k = tid - 8192;
        const int rowblk = k >> 9, kk = (k >> 6) & 7, lane = k & 63;
        const int oc = rowblk * 16 + (lane & 15), c0 = kk * 32 + (lane >> 4) * 8;
        const float* src = qw + oc * 256 + c0;
        unsigned short h[8], l[8];
        #pragma unroll
        for (int e = 0; e < 8; ++e) {
            h[e] = f2bf(src[e]);
            l[e] = f2bf(src[e] - bf2f(h[e]));
        }
        *(uint4*)(wqFh + (size_t)k * 8) = pack8(h);
        *(uint4*)(wqFl + (size_t)k * 8) = pack8(l);
    }
}

// ---------------------------------------------------------------------------
// Kernel 1: MFMA projections (R6 verbatim — passed).
// ---------------------------------------------------------------------------
__global__ __launch_bounds__(256, 4) void proj_kernel(
    const float* __restrict__ x, const unsigned short* __restrict__ wqFh,
    const unsigned short* __restrict__ wqFl, const unsigned short* __restrict__ wvF,
    const float* __restrict__ qb, const float* __restrict__ vb,
    unsigned short* __restrict__ qh, unsigned short* __restrict__ ql,
    unsigned short* __restrict__ vF)
{
    __shared__ __align__(16) unsigned short S[10240];

    const int t    = threadIdx.x;
    const int lane = t & 63;
    const int w    = t >> 6;
    const int q4   = lane >> 4;
    const int l15  = lane & 15;
    const int b    = blockIdx.x & 7;          // batch -> XCD pin
    const int tt   = blockIdx.x >> 3;         // 0..127, n-tile of 32
    const int i0   = tt * 32;

    {
        const int n  = lane & 31;
        const int hi = lane >> 5;
        const float* xb = x + (size_t)b * C_ * N_ + i0 + n;
        #pragma unroll
        for (int cc = 0; cc < 4; ++cc) {
            const int chi = w * 8 + cc * 2 + hi;
            float v[8];
            #pragma unroll
            for (int e = 0; e < 8; ++e) v[e] = xb[(size_t)(chi * 8 + e) * N_];
            unsigned short h[8];
            #pragma unroll
            for (int e = 0; e < 8; ++e) h[e] = f2bf(v[e]);
            *(uint4*)&S[(chi * 32 + (n ^ (chi & 3))) * 8] = pack8(h);
        }
    }
    __syncthreads();

    f4_t acc[4][2];
    #pragma unroll
    for (int mt = 0; mt < 4; ++mt)
        #pragma unroll
        for (int nt = 0; nt < 2; ++nt) acc[mt][nt] = (f4_t)0.0f;
    f4_t qacc[2];
    qacc[0] = (f4_t)0.0f; qacc[1] = (f4_t)0.0f;

    #pragma unroll
    for (int kk = 0; kk < 8; ++kk) {
        bf8_t Bh[2];
        #pragma unroll
        for (int nt = 0; nt < 2; ++nt)
            Bh[nt] = *(const bf8_t*)&S[((kk * 4 + q4) * 32 + nt * 16 + (l15 ^ q4)) * 8];
        bf8_t Av[4];
        #pragma unroll
        for (int mt = 0; mt < 4; ++mt)
            Av[mt] = *(const bf8_t*)&wvF[(size_t)(((w * 4 + mt) * 8 + kk) * 64 + lane) * 8];

        #pragma unroll
        for (int mt = 0; mt < 4; ++mt)
            #pragma unroll
            for (int nt = 0; nt < 2; ++nt)
                acc[mt][nt] = __builtin_amdgcn_mfma_f32_16x16x32_bf16(
                    Av[mt], Bh[nt], acc[mt][nt], 0, 0, 0);

        if (w < 2) {
            #pragma unroll
            for (int mq = 0; mq < 2; ++mq) {
                bf8_t Aqh = *(const bf8_t*)&wqFh[(size_t)((mq * 8 + kk) * 64 + lane) * 8];
                bf8_t Aql = *(const bf8_t*)&wqFl[(size_t)((mq * 8 + kk) * 64 + lane) * 8];
                qacc[mq] = __builtin_amdgcn_mfma_f32_16x16x32_bf16(Aqh, Bh[w], qacc[mq], 0, 0, 0);
                qacc[mq] = __builtin_amdgcn_mfma_f32_16x16x32_bf16(Aql, Bh[w], qacc[mq], 0, 0, 0);
            }
        }
    }

    if (w < 2) {
        const int iq = i0 + w * 16 + l15;
        #pragma unroll
        for (int mq = 0; mq < 2; ++mq) {
            float4 qb4 = *(const float4*)(qb + mq * 16 + q4 * 4);
            float qv[4] = {qacc[mq][0] + qb4.x, qacc[mq][1] + qb4.y,
                           qacc[mq][2] + qb4.z, qacc[mq][3] + qb4.w};
            unsigned short hr[4], lr[4];
            #pragma unroll
            for (int r = 0; r < 4; ++r) {
                hr[r] = f2bf(qv[r]);
                lr[r] = f2bf(qv[r] - bf2f(hr[r]));
            }
            uint2 uh, ul;
            uh.x = hr[0] | ((unsigned)hr[1] << 16); uh.y = hr[2] | ((unsigned)hr[3] << 16);
            ul.x = lr[0] | ((unsigned)lr[1] << 16); ul.y = lr[2] | ((unsigned)lr[3] << 16);
            size_t qoff = ((size_t)b * N_ + iq) * D_ + mq * 16 + q4 * 4;
            *(uint2*)(qh + qoff) = uh;
            *(uint2*)(ql + qoff) = ul;
        }
    }

    __syncthreads();
    #pragma unroll
    for (int mt = 0; mt < 4; ++mt) {
        float4 vb4 = *(const float4*)(vb + w * 64 + mt * 16 + q4 * 4);
        float bias[4] = {vb4.x, vb4.y, vb4.z, vb4.w};
        #pragma unroll
        for (int nt = 0; nt < 2; ++nt)
            #pragma unroll
            for (int r = 0; r < 4; ++r)
                S[(w * 64 + mt * 16 + q4 * 4 + r) * 40 + nt * 16 + l15] =
                    f2bf(acc[mt][nt][r] + bias[r]);
    }
    __syncthreads();
    #pragma unroll
    for (int k2 = 0; k2 < 4; ++k2) {
        int id  = k2 * 256 + t;
        int oc  = id >> 2, seg = id & 3;
        uint4 dat = *(const uint4*)&S[oc * 40 + seg * 8];
        size_t p  = (size_t)(tt & 1) * 4 + seg;
        size_t off = ((((size_t)b * 64 + (tt >> 1)) * 8 + p) * 256 + (oc ^ seg)) * 8;
        *(uint4*)(vF + off) = dat;
    }
}

// ---------------------------------------------------------------------------
// Kernel 2: MFMA flash attention.
// R9 = R7 with the inline-asm v_cvt_pk_bf16_f32 REVERTED to scalar f2bf
// (prime correctness suspect: unverifiable operand->half placement; guide
// m240 explicitly says don't hand-write it). Kept from R7:
//  (a) PSWZ2 (concrete-trace audited consistent, write & read),
//  (b) unroll-2 with compile-time cur + hoisted index arrays,
//  (c) rolling K/V pointers, (d) setprio removed.
// ---------------------------------------------------------------------------
__global__ __launch_bounds__(256, 2) void attn_kernel(
    const unsigned short* __restrict__ qh, const unsigned short* __restrict__ ql,
    const unsigned short* __restrict__ vF, const float* __restrict__ x,
    const float* __restrict__ gamma_p, float* __restrict__ out)
{
    __shared__ __align__(16) unsigned char SMEM[2 * VBUF];   // V dbuf / epilogue T
    __shared__ __align__(16) unsigned short Pb[2][4096];     // P dbuf (swizzled)
    float* T    = (float*)SMEM;
    float* rowl = (float*)&Pb[0][0];                         // epilogue alias

    const int t    = threadIdx.x;
    const int lane = t & 63;
    const int w    = t >> 6;
    const int q4   = lane >> 4;
    const int l15  = lane & 15;
    const int b    = blockIdx.x & 7;              // batch -> XCD pin
    const int i0   = (blockIdx.x >> 3) * 64;

    const unsigned short* qhb = qh + (size_t)b * N_ * D_;
    const unsigned short* qlb = ql + (size_t)b * N_ * D_;
    const unsigned short* vFb = vF + (size_t)b * 1048576;

    bf8_t Ah[4], Al[4];
    #pragma unroll
    for (int mt = 0; mt < 4; ++mt) {
        size_t off = (size_t)(i0 + mt * 16 + l15) * D_ + q4 * 8;
        Ah[mt] = *(const bf8_t*)(qhb + off);
        Al[mt] = *(const bf8_t*)(qlb + off);
    }

    // ---- hoisted loop-invariant LDS indices (compile-time-indexed arrays) ----
    const int jl = w * 16 + l15;
    const int pprt = jl >> 3, jlo = jl & 7;
    int pwIdx[4][4];           // P write: u16 index within Pb[cur]
    #pragma unroll
    for (int mt = 0; mt < 4; ++mt)
        #pragma unroll
        for (int r = 0; r < 4; ++r) {
            int u = pprt * 64 + mt * 16 + q4 * 4 + r;
            pwIdx[mt][r] = PSWZ2(u) * 8 + jlo;
        }
    int rdIdx[2][4];           // P read (Af): u16 index
    #pragma unroll
    for (int kk = 0; kk < 2; ++kk)
        #pragma unroll
        for (int mt = 0; mt < 4; ++mt) {
            int u = (kk * 4 + q4) * 64 + mt * 16 + l15;
            rdIdx[kk][mt] = PSWZ2(u) * 8;
        }
    int bfOff[2][4];           // V read (Bf): byte offset within buffer
    #pragma unroll
    for (int kk = 0; kk < 2; ++kk)
        #pragma unroll
        for (int nt = 0; nt < 4; ++nt)
            bfOff[kk][nt] = (kk * 4 + q4) * 4096 +
                            ((w * 64 + nt * 16 + l15) ^ q4) * 16;

    f4_t acc[4][4];
    #pragma unroll
    for (int mt = 0; mt < 4; ++mt)
        #pragma unroll
        for (int nt = 0; nt < 4; ++nt) acc[mt][nt] = (f4_t)0.0f;

    f4_t lacc[4];
    #pragma unroll
    for (int mt = 0; mt < 4; ++mt) lacc[mt] = (f4_t)0.0f;
    bf8_t onesb;
    #pragma unroll
    for (int e = 0; e < 8; ++e) onesb[e] = (short)0x3F80;

    // rolling pointers
    const int koffBase = jl * D_ + q4 * 8;
    const unsigned short* khp = qhb + 2048 + koffBase;   // K tile jt+1
    const unsigned short* klp = qlb + 2048 + koffBase;
    const unsigned short* vjp = vFb + 16384;             // V tile jt+1

    // prologue: K(0), stage V tile 0 into buffer 0
    bf8_t Bh = *(const bf8_t*)(qhb + koffBase);
    bf8_t Bl = *(const bf8_t*)(qlb + koffBase);
    {
        const unsigned short* vj = vFb;
        #pragma unroll
        for (int i = 0; i < 8; ++i) {
            const int c = i * 4 + w;
            gload_lds16(vj + c * 512 + lane * 8, &SMEM[c * 1024]);
        }
    }

    auto body = [&](int jt, auto ic) {
        constexpr int cur = decltype(ic)::v;
        unsigned short* Pbc = &Pb[cur][0];
        const unsigned char* Vsc = &SMEM[cur * VBUF];

        // QK^T for tile jt (K regs loaded last body / prologue)
        f4_t s[4];
        #pragma unroll
        for (int mt = 0; mt < 4; ++mt) {
            f4_t a = (f4_t)0.0f;
            a = __builtin_amdgcn_mfma_f32_16x16x32_bf16(Ah[mt], Bh, a, 0, 0, 0);
            a = __builtin_amdgcn_mfma_f32_16x16x32_bf16(Ah[mt], Bl, a, 0, 0, 0);
            a = __builtin_amdgcn_mfma_f32_16x16x32_bf16(Al[mt], Bh, a, 0, 0, 0);
            s[mt] = a;
        }

        // exp + scalar bf16 convert (f2bf — proven path; cvt_pk asm reverted)
        #pragma unroll
        for (int mt = 0; mt < 4; ++mt)
            #pragma unroll
            for (int r = 0; r < 4; ++r)
                Pbc[pwIdx[mt][r]] = f2bf(__expf(s[mt][r] - FMX));

        __syncthreads();   // P(jt) visible; STAGE(jt) DMA drained

        // K(jt+1) then STAGE(jt+1) into the other buffer
        if (jt + 1 < N_ / 64) {
            Bh = *(const bf8_t*)khp;
            Bl = *(const bf8_t*)klp;
            khp += 2048; klp += 2048;
            #pragma unroll
            for (int i = 0; i < 8; ++i) {
                const int c = i * 4 + w;
                gload_lds16(vjp + c * 512 + lane * 8,
                            &SMEM[(cur ^ 1) * VBUF + c * 1024]);
            }
            vjp += 16384;
        }

        // PV for tile jt
        #pragma unroll
        for (int kk = 0; kk < 2; ++kk) {
            bf8_t Af[4], Bf[4];
            #pragma unroll
            for (int nt = 0; nt < 4; ++nt)
                Bf[nt] = *(const bf8_t*)&Vsc[bfOff[kk][nt]];
            #pragma unroll
            for (int mt = 0; mt < 4; ++mt)
                Af[mt] = *(const bf8_t*)&Pbc[rdIdx[kk][mt]];
            #pragma unroll
            for (int mt = 0; mt < 4; ++mt)
                #pragma unroll
                for (int nt = 0; nt < 4; ++nt)
                    acc[mt][nt] = __builtin_amdgcn_mfma_f32_16x16x32_bf16(
                        Af[mt], Bf[nt], acc[mt][nt], 0, 0, 0);
            if (w == 3) {
                #pragma unroll
                for (int mt = 0; mt < 4; ++mt)
                    lacc[mt] = __builtin_amdgcn_mfma_f32_16x16x32_bf16(
                        Af[mt], onesb, lacc[mt], 0, 0, 0);
            }
        }
    };

    for (int jtp = 0; jtp < N_ / 64; jtp += 2) {
        body(jtp,     IC0{});
        body(jtp + 1, IC1{});
    }

    __syncthreads();
    if (w == 3 && l15 == 0) {
        #pragma unroll
        for (int mt = 0; mt < 4; ++mt)
            #pragma unroll
            for (int r = 0; r < 4; ++r)
                rowl[mt * 16 + q4 * 4 + r] = lacc[mt][r];
    }
    __syncthreads();

    const float g = gamma_p[0];
    for (int mt = 0; mt < 4; ++mt) {
        float4 rl = *(float4*)(&rowl[mt * 16 + q4 * 4]);
        float inv[4] = { g / rl.x, g / rl.y, g / rl.z, g / rl.w };
        #pragma unroll
        for (int nt = 0; nt < 4; ++nt)
            #pragma unroll
            for (int r = 0; r < 4; ++r)
                T[(w * 64 + nt * 16 + l15) * 17 + q4 * 4 + r] = acc[mt][nt][r] * inv[r];
        __syncthreads();
        #pragma unroll
        for (int pass = 0; pass < 4; ++pass) {
            int c  = pass * 64 + (t >> 2);
            int ii = (t & 3) * 4;
            float4 o;
            o.x = T[c * 17 + ii];     o.y = T[c * 17 + ii + 1];
            o.z = T[c * 17 + ii + 2]; o.w = T[c * 17 + ii + 3];
            size_t goff = ((size_t)b * C_ + c) * N_ + i0 + mt * 16 + ii;
            float4 xv = *(const float4*)(x + goff);
            o.x += xv.x; o.y += xv.y; o.z += xv.z; o.w += xv.w;
            *(float4*)(out + goff) = o;
        }
        __syncthreads();
    }
}

extern "C" void kernel_launch(void* const* d_in, const int* in_sizes, int n_in,
                              void* d_out, int out_size, void* d_ws, size_t ws_size,
                              hipStream_t stream)
{
    const float* x     = (const float*)d_in[0];
    const float* q_w   = (const float*)d_in[1];
    const float* q_b   = (const float*)d_in[2];
    const float* v_w   = (const float*)d_in[3];
    const float* v_b   = (const float*)d_in[4];
    const float* gamma = (const float*)d_in[5];
    float* out = (float*)d_out;

    unsigned short* ws16 = (unsigned short*)d_ws;
    unsigned short* qhp  = ws16;                   // 1M u16
    unsigned short* qlp  = ws16 + 1048576;         // 1M u16
    unsigned short* vFp  = ws16 + 2097152;         // 8M u16 (fragment-order V, c^p swizzled)
    unsigned short* wvF  = ws16 + 10485760;        // 64K u16
    unsigned short* wqFh = wvF + 65536;            // 8K u16
    unsigned short* wqFl = wqFh + 8192;            // 8K u16

    wprep_kernel<<<36, 256, 0, stream>>>(q_w, v_w, wqFh, wqFl, wvF);
    proj_kernel<<<B_ * (N_ / 32), 256, 0, stream>>>(x, wqFh, wqFl, wvF, q_b, v_b,
                                                    qhp, qlp, vFp);
    attn_kernel<<<B_ * (N_ / 64), 256, 0, stream>>>(qhp, qlp, vFp, x, gamma, out);
}